// Round 3
// baseline (517.441 us; speedup 1.0000x reference)
//
#include <hip/hip_runtime.h>
#include <hip/hip_bf16.h>
#include <math.h>

#define BATCH 4096
#define HID 256
#define OUT_W 15
#define AK 448   // padded K for obs GEMM (400 valid + 48 zeros)

typedef unsigned short ushort_t;
typedef unsigned int uint_t;

using bf16x8 = __attribute__((ext_vector_type(8))) short;
using f32x4v = __attribute__((ext_vector_type(4))) float;

__device__ __forceinline__ float sigf(float x) { return 1.0f / (1.0f + __expf(-x)); }
__device__ __forceinline__ float tanh_fast(float x) { return 1.0f - 2.0f / (__expf(2.0f * x) + 1.0f); }
__device__ __forceinline__ float bf2f(ushort_t u) { return __uint_as_float(((uint_t)u) << 16); }
__device__ __forceinline__ ushort_t f2bf(float x) {
    uint_t b = __float_as_uint(x);
    return (ushort_t)((b + 0x7fffu + ((b >> 16) & 1u)) >> 16);
}

// ---------------------------------------------------------------------------
// Prep: W_ih transpose, per-step biases, samp tables, mlp transposes,
// packed conv1 weights w1p[ic][12], conv2 B-fragments Btg[tap][oc][ic] bf16,
// W_hh -> bf16 [n][k], W_obs -> bf16 [col][k=448 padded].
// ---------------------------------------------------------------------------
__global__ __launch_bounds__(256) void prep_kernel(
    const float* __restrict__ W_ih, const float* __restrict__ W_hh,
    const float* __restrict__ b_ih, const float* __restrict__ b_hh,
    const float* __restrict__ addr_emb, const float* __restrict__ pid_emb,
    const float* __restrict__ sid_emb,
    const float* __restrict__ mlp_w2, const float* __restrict__ mlp_w3,
    const float* __restrict__ conv1_w, const float* __restrict__ conv1_b,
    const float* __restrict__ conv2_w,
    float* __restrict__ W_ih_T, ushort_t* __restrict__ Wb,
    float* __restrict__ bias_all, float* __restrict__ pid_rows,
    float* __restrict__ sid_rows, float* __restrict__ w2t, float* __restrict__ w3t,
    float* __restrict__ w1p, ushort_t* __restrict__ Btg,
    ushort_t* __restrict__ Wobs_b)
{
    int blk = blockIdx.x, t = threadIdx.x;
    if (blk < 112) {
        // W_ih (1024x432) -> W_ih_T (432x1024)
        __shared__ float tile[64][65];
        int j0 = (blk & 15) * 64;
        int k0 = (blk >> 4) * 64;
        for (int i = t; i < 4096; i += 256) {
            int r = i >> 6, c = i & 63;
            int k = k0 + c;
            tile[r][c] = (k < 432) ? W_ih[(size_t)(j0 + r) * 432 + k] : 0.f;
        }
        __syncthreads();
        for (int i = t; i < 4096; i += 256) {
            int r = i >> 6, c = i & 63;
            int k = k0 + r;
            if (k < 432) W_ih_T[(size_t)k * 1024 + j0 + c] = tile[c][r];
        }
    } else if (blk == 112) {
        const int aids[7] = {0, 1, 4, 2, 3, 5, 6};
        for (int s = 0; s < 7; s++) {
            int aid = aids[s];
            for (int j = t; j < 1024; j += 256) {
                float v = b_ih[j] + b_hh[j];
                #pragma unroll
                for (int k = 0; k < 16; k++)
                    v += addr_emb[aid * 16 + k] * W_ih[(size_t)j * 432 + 416 + k];
                bias_all[s * 1024 + j] = v;
            }
        }
    } else if (blk == 113) {
        for (int p = 0; p < 3; p++)
            for (int j = t; j < 1024; j += 256) {
                float v = 0.f;
                #pragma unroll
                for (int k = 0; k < 16; k++)
                    v += pid_emb[p * 16 + k] * W_ih[(size_t)j * 432 + 400 + k];
                pid_rows[p * 1024 + j] = v;
            }
        for (int p = 0; p < 2; p++)
            for (int j = t; j < 1024; j += 256) {
                float v = 0.f;
                #pragma unroll
                for (int k = 0; k < 16; k++)
                    v += sid_emb[p * 16 + k] * W_ih[(size_t)j * 432 + 400 + k];
                sid_rows[p * 1024 + j] = v;
            }
    } else if (blk == 114) {
        for (int i = t; i < 10000; i += 256) {
            int o = i / 100, k = i % 100;
            w2t[k * 100 + o] = mlp_w2[i];
        }
        for (int i = t; i < 1600; i += 256) {
            int o = i / 100, k = i % 100;
            w3t[k * 16 + o] = mlp_w3[i];
        }
    } else if (blk == 115) {
        for (int i = t; i < 384; i += 256) {
            int ic = i / 12, k = i % 12;
            float v = 0.f;
            if (k < 9) v = conv1_w[ic * 9 + k];
            else if (k == 9) v = conv1_b[ic];
            w1p[i] = v;
        }
        // Btg[(tap*16 + oc)*32 + ic] = conv2_w[(oc*32+ic)*9 + tap]
        for (int i = t; i < 4608; i += 256) {
            int tap = i >> 9;
            int rem = i & 511;
            int oc = rem >> 5, ic = rem & 31;
            Btg[i] = f2bf(conv2_w[(size_t)(oc * 32 + ic) * 9 + tap]);
        }
    } else if (blk < 124) {
        // W_hh (1024x256) fp32 -> bf16, same [n][k] layout
        int seg = blk - 116;  // 0..7
        for (int i = seg * 32768 + t; i < (seg + 1) * 32768; i += 256)
            Wb[i] = f2bf(W_hh[i]);
    } else {
        // W_obs rows of W_ih -> bf16 [col][448], k >= 400 zero
        int col0 = (blk - 124) * 64;  // 16 blocks x 64 cols
        for (int i = t; i < 64 * AK; i += 256) {
            int c = col0 + i / AK, k = i % AK;
            Wobs_b[(size_t)c * AK + k] = (k < 400) ? f2bf(W_ih[(size_t)c * 432 + k]) : (ushort_t)0;
        }
    }
}

// ---------------------------------------------------------------------------
// Conv encoder v5: two half-image phases over a 17-row ring buffer.
//   512 threads, LDS ~70 KB -> 2 blocks/CU (16 waves/CU).
//   conv1 thread decomposition (r = t>>5, g = (t>>2)&7, icq = t&3):
//     row 16ph+r, cols 4g..4g+3, ics 8icq..8icq+7.  Patch Pt[3][12] loaded
//     once/phase; weights register-resident per 4-ic half; all 8 ic of a
//     position packed in regs (v_cvt_pk_bf16_f32) and written as ONE uint4
//     -> bank-uniform writes (was two 8B writes at 8-way conflict).
//   conv2: output rows 8ph..8ph+7, 1 row/wave, 9 tap-MFMAs.
//   Ring: buffer row = (c1row+1) mod 17 -> halo row (c1 row 15) free.
//   cE: even cols 0..30 (16 pos), cO: odd cols -1..31 (17 pos), pos stride
//   40 ushorts (80 B) -> conflict-free A-frag ds_read_b128.
//   Epilogue pool writes obs_emb as bf16 padded to 448 (k>=400 zero).
// ---------------------------------------------------------------------------
#define CE_RS 640   // cE row stride in ushorts (16 pos * 40)
#define CO_RS 680   // cO row stride in ushorts (17 pos * 40)
__global__ __launch_bounds__(512, 4) void conv_kernel(
    const float* __restrict__ obs, const float* __restrict__ w1p,
    const ushort_t* __restrict__ Btg, const float* __restrict__ b2,
    ushort_t* __restrict__ obs_emb_b)
{
    __shared__ __align__(16) ushort_t cE[17 * CE_RS];  // 21760 B
    __shared__ __align__(16) ushort_t cO[17 * CO_RS];  // 23120 B
    __shared__ __align__(16) float c2s[16 * 260];      // 16640 B
    __shared__ __align__(16) float sm2[33 * 68];       // 8976 B
    __shared__ __align__(16) float w1s[384];           // 1536 B
    const int b = blockIdx.x, t = threadIdx.x;
    const float* og = obs + (size_t)b * 4096;

    const int w = t >> 6, L = t & 63, q = L >> 4, ln = L & 15;

    // conv2 B-fragments (same for every wave; L1-resident)
    bf16x8 Bv[9];
    #pragma unroll
    for (int tap = 0; tap < 9; tap++)
        Bv[tap] = *reinterpret_cast<const bf16x8*>(&Btg[(tap * 16 + ln) * 32 + q * 8]);

    // zero: cE buffer row 0 (c1 row -1), cO row 0, cO pos0 (col -1) rows 1..16
    {
        uint_t* zE = (uint_t*)cE;
        uint_t* zO = (uint_t*)cO;
        for (int i = t; i < CE_RS / 2; i += 512) zE[i] = 0;
        for (int i = t; i < CO_RS / 2; i += 512) zO[i] = 0;
        if (t < 320) {
            int row = (t / 20) + 1, d = t % 20;
            zO[row * (CO_RS / 2) + d] = 0;
        }
    }
    if (t < 96) ((float4*)w1s)[t] = ((const float4*)w1p)[t];
    if (t < 33) sm2[t * 68 + 3] = 0.f;  // img col -1 = 0, all staged rows

    // stage obs rows 32ph-1 .. 32ph+31 -> sm2 rows 0..32 (img col j at 4+j)
    auto stage_obs = [&](int ph) {
        for (int i = t; i < 33 * 16; i += 512) {
            int row = i >> 4, c4 = i & 15;
            int orow = 32 * ph - 1 + row;
            float4 v = float4{0.f, 0.f, 0.f, 0.f};
            if (orow >= 0) v = ((const float4*)(og + (size_t)orow * 64))[c4];
            *(float4*)&sm2[row * 68 + 4 + 4 * c4] = v;
        }
    };

    // conv1 phase: thread (r = t>>5, g = (t>>2)&7, icq = t&3) computes
    // c1 row 16ph+r, cols 4g..4g+3, ics 8icq..8icq+7.
    // Buffer row = (c1row+1) mod 17 = ph ? r : r+1.
    auto conv1_phase = [&](int ph) {
        const int r = t >> 5, g = (t >> 2) & 7, icq = t & 3;
        const int brow = ph ? r : (r + 1);
        // Pt[d][j] = obs[2*(16ph+r)-1+d][8g-4+j]; needed col for pos p, tap dx
        // is 8g+2p-1+dx -> j = 2p+3+dx.
        float Pt[3][12];
        #pragma unroll
        for (int d = 0; d < 3; d++) {
            const float* src = &sm2[(2 * r + d) * 68 + 8 * g];
            #pragma unroll
            for (int j4 = 0; j4 < 3; j4++) {
                float4 v = ((const float4*)src)[j4];
                Pt[d][j4 * 4 + 0] = v.x; Pt[d][j4 * 4 + 1] = v.y;
                Pt[d][j4 * 4 + 2] = v.z; Pt[d][j4 * 4 + 3] = v.w;
            }
        }
        uint_t pk[4][4];  // [pos][4 dwords = 8 ic bf16]
        #pragma unroll
        for (int ih = 0; ih < 2; ih++) {
            float W[4][10];
            #pragma unroll
            for (int i = 0; i < 4; i++) {
                const float* qw = &w1s[(icq * 8 + ih * 4 + i) * 12];
                float4 qa = *(const float4*)qw;
                float4 qb = *(const float4*)(qw + 4);
                float2 qc = *(const float2*)(qw + 8);
                W[i][0] = qa.x; W[i][1] = qa.y; W[i][2] = qa.z; W[i][3] = qa.w;
                W[i][4] = qb.x; W[i][5] = qb.y; W[i][6] = qb.z; W[i][7] = qb.w;
                W[i][8] = qc.x; W[i][9] = qc.y;
            }
            #pragma unroll
            for (int p = 0; p < 4; p++) {
                float sv[4];
                #pragma unroll
                for (int i = 0; i < 4; i++) {
                    float s = W[i][9];
                    #pragma unroll
                    for (int d = 0; d < 3; d++)
                        #pragma unroll
                        for (int dx = 0; dx < 3; dx++)
                            s += W[i][d * 3 + dx] * Pt[d][2 * p + 3 + dx];
                    sv[i] = fmaxf(s, 0.f);
                }
                uint_t w0, w1;
                asm("v_cvt_pk_bf16_f32 %0, %1, %2" : "=v"(w0) : "v"(sv[0]), "v"(sv[1]));
                asm("v_cvt_pk_bf16_f32 %0, %1, %2" : "=v"(w1) : "v"(sv[2]), "v"(sv[3]));
                pk[p][ih * 2 + 0] = w0;
                pk[p][ih * 2 + 1] = w1;
            }
        }
        #pragma unroll
        for (int p = 0; p < 4; p++) {
            int c = 4 * g + p;
            ushort_t* dst = (c & 1)
                ? &cO[brow * CO_RS + ((c + 1) >> 1) * 40 + icq * 8]
                : &cE[brow * CE_RS + (c >> 1) * 40 + icq * 8];
            *(uint4*)dst = uint4{pk[p][0], pk[p][1], pk[p][2], pk[p][3]};
        }
    };

    // conv2 phase: wave w -> output row y = 8ph+w; 9 tap-MFMAs; epilogue to c2s
    auto conv2_phase = [&](int ph) {
        const int y = 8 * ph + w;
        f32x4v C = {0.f, 0.f, 0.f, 0.f};
        #pragma unroll
        for (int dy = 0; dy < 3; dy++) {
            int br = 2 * y + dy;          // (c1row+1); c1row = 2y-1+dy
            if (br >= 17) br -= 17;
            bf16x8 a0 = *reinterpret_cast<const bf16x8*>(&cO[br * CO_RS + ln * 40 + q * 8]);        // dx=0: col 2m-1
            bf16x8 a1 = *reinterpret_cast<const bf16x8*>(&cE[br * CE_RS + ln * 40 + q * 8]);        // dx=1: col 2m
            bf16x8 a2 = *reinterpret_cast<const bf16x8*>(&cO[br * CO_RS + (ln + 1) * 40 + q * 8]);  // dx=2: col 2m+1
            C = __builtin_amdgcn_mfma_f32_16x16x32_bf16(a0, Bv[dy * 3 + 0], C, 0, 0, 0);
            C = __builtin_amdgcn_mfma_f32_16x16x32_bf16(a1, Bv[dy * 3 + 1], C, 0, 0, 0);
            C = __builtin_amdgcn_mfma_f32_16x16x32_bf16(a2, Bv[dy * 3 + 2], C, 0, 0, 0);
        }
        float bb2 = b2[ln];
        float4 o;
        o.x = fmaxf(C[0] + bb2, 0.f);
        o.y = fmaxf(C[1] + bb2, 0.f);
        o.z = fmaxf(C[2] + bb2, 0.f);
        o.w = fmaxf(C[3] + bb2, 0.f);
        *(float4*)&c2s[ln * 260 + y * 16 + q * 4] = o;  // oc=ln, x=q*4+r
    };

    stage_obs(0);
    __syncthreads();
    conv1_phase(0);            // writes buffer rows 1..16 (c1 rows 0..15)
    __syncthreads();
    stage_obs(1);              // global loads overlap phase-0 MFMAs
    conv2_phase(0);            // reads rows 0..16; c2 rows 0..7
    __syncthreads();
    conv1_phase(1);            // writes buffer rows 0..15 (c1 rows 16..31); row 16 (c1 15) preserved
    __syncthreads();
    conv2_phase(1);            // c2 rows 8..15
    __syncthreads();

    // pool 3x3 stride 3 -> obs_emb bf16 [b][448] (400 valid + zeros)
    if (t < 400) {
        int c = t / 25, rem = t % 25, py = rem / 5, px = rem % 5;
        float s = 0.f;
        #pragma unroll
        for (int dy = 0; dy < 3; dy++)
            #pragma unroll
            for (int dx = 0; dx < 3; dx++)
                s += c2s[c * 260 + (3 * py + dy) * 16 + 3 * px + dx];
        obs_emb_b[(size_t)b * AK + t] = f2bf(s * (1.f / 9.f));
    } else if (t < AK) {
        obs_emb_b[(size_t)b * AK + t] = 0;
    }
}

// ---------------------------------------------------------------------------
// obs_part (bf16) = obs_emb_b (B x 448 bf16) @ Wobs_b.T -> (B x 1024), MFMA.
// Grid: 64 row-blocks x 8 col-blocks; 256 thr (4 waves); wave w -> rows
// m0=w*16; 8 col-tiles of 16 per wave; K loop: 7 chunks of 64 staged in LDS.
// ---------------------------------------------------------------------------
__global__ __launch_bounds__(256) void obs_gemm(
    const ushort_t* __restrict__ Ab, const ushort_t* __restrict__ Wob,
    ushort_t* __restrict__ outp)
{
    __shared__ __align__(16) ushort_t As[64 * 72];  // 9216 B, row stride 144 B
    const int t = threadIdx.x;
    const int bm = blockIdx.x & 63, bu = blockIdx.x >> 6;
    const int b0 = bm * 64, n0 = bu * 128;
    const int w = t >> 6, L = t & 63, q = L >> 4, ln = L & 15;
    const int m0 = w * 16;

    f32x4v acc[8];
    #pragma unroll
    for (int i = 0; i < 8; i++) acc[i] = f32x4v{0.f, 0.f, 0.f, 0.f};

    for (int kc = 0; kc < 7; kc++) {
        // stage A chunk: 64 rows x 64 k (bf16)
        #pragma unroll
        for (int ii = 0; ii < 2; ii++) {
            int i = t + ii * 256;
            int row = i >> 3, c8 = i & 7;
            *(uint4*)&As[row * 72 + c8 * 8] =
                *(const uint4*)&Ab[(size_t)(b0 + row) * AK + kc * 64 + c8 * 8];
        }
        __syncthreads();
        bf16x8 a[2];
        #pragma unroll
        for (int ks = 0; ks < 2; ks++)
            a[ks] = *reinterpret_cast<const bf16x8*>(&As[(m0 + ln) * 72 + ks * 32 + q * 8]);
        #pragma unroll
        for (int ct = 0; ct < 8; ct++) {
            const ushort_t* wr = Wob + (size_t)(n0 + ct * 16 + ln) * AK + kc * 64 + q * 8;
            bf16x8 bv0 = *reinterpret_cast<const bf16x8*>(wr);
            bf16x8 bv1 = *reinterpret_cast<const bf16x8*>(wr + 32);
            acc[ct] = __builtin_amdgcn_mfma_f32_16x16x32_bf16(a[0], bv0, acc[ct], 0, 0, 0);
            acc[ct] = __builtin_amdgcn_mfma_f32_16x16x32_bf16(a[1], bv1, acc[ct], 0, 0, 0);
        }
        __syncthreads();
    }
    #pragma unroll
    for (int ct = 0; ct < 8; ct++) {
        int col = n0 + ct * 16 + ln;
        #pragma unroll
        for (int j = 0; j < 4; j++) {
            int row = b0 + m0 + q * 4 + j;
            outp[(size_t)row * 1024 + col] = f2bf(acc[ct][j]);
        }
    }
}

// ---------------------------------------------------------------------------
// step0 elementwise: h=c=0 -> c0 (fp32), hb0 (bf16). pre = obs_part + bias0.
// ---------------------------------------------------------------------------
__global__ __launch_bounds__(256) void step0_ew(
    const ushort_t* __restrict__ obs_part, const float* __restrict__ bias_s,
    float* __restrict__ c_out, ushort_t* __restrict__ hb_out)
{
    const int R = blockIdx.x, u = threadIdx.x;
    float pre[4];
    #pragma unroll
    for (int g = 0; g < 4; g++)
        pre[g] = bf2f(obs_part[(size_t)R * 1024 + g * 256 + u]) + bias_s[g * 256 + u];
    float c2 = sigf(pre[0]) * tanh_fast(pre[2]);
    float hv = sigf(pre[3]) * tanh_fast(c2);
    c_out[(size_t)R * 256 + u] = c2;
    hb_out[(size_t)R * 256 + u] = f2bf(hv);
}

// ---------------------------------------------------------------------------
// MFMA LSTM step.  DUAL=1: 1024 blocks, two independent steps in one launch
// (per-half pointer sets; both halves share Wb/samp_rows/obs_part).
// ---------------------------------------------------------------------------
template <int SAMP, int HEAD_N, int DUAL>
__global__ __launch_bounds__(512, 4) void lstm_mfma(
    const ushort_t* __restrict__ hb_in, const float* __restrict__ c_in,
    ushort_t* __restrict__ hb_out, float* __restrict__ c_out,
    const ushort_t* __restrict__ obs_part, const float* __restrict__ bias_s,
    const float* __restrict__ samp_rows, const int* __restrict__ samp_idx,
    const float* __restrict__ rp0_emb, const float* __restrict__ WsampT,
    const ushort_t* __restrict__ Wb,
    const float* __restrict__ head_w, const float* __restrict__ head_b,
    float* __restrict__ out, int out_off,
    const ushort_t* __restrict__ hb_in2, const float* __restrict__ c_in2,
    ushort_t* __restrict__ hb_out2, float* __restrict__ c_out2,
    const float* __restrict__ bias_s2, const int* __restrict__ samp_idx2,
    const float* __restrict__ head_w2, int out_off2)
{
    __shared__ ushort_t hAs[64 * 264];   // 33792 B, row stride 528 B
    __shared__ float hws[3 * 256];       // head weights
    __shared__ float red[64 * 8 * 3];    // head partials
    const int t = threadIdx.x;
    const int half  = DUAL ? (int)(blockIdx.x >> 9) : 0;
    const int inner = DUAL ? (int)(blockIdx.x & 511) : (int)blockIdx.x;
    const int bm = inner & 63, bu = inner >> 6;
    const int b0 = bm * 64;

    const ushort_t* hbi = (DUAL && half) ? hb_in2 : hb_in;
    const float* cip    = (DUAL && half) ? c_in2 : c_in;
    ushort_t* hbo       = (DUAL && half) ? hb_out2 : hb_out;
    float* cop          = (DUAL && half) ? c_out2 : c_out;
    const float* biasp  = (DUAL && half) ? bias_s2 : bias_s;
    const int* sidx     = (DUAL && half) ? samp_idx2 : samp_idx;
    const float* hwp    = (DUAL && half) ? head_w2 : head_w;
    const int ooff      = (DUAL && half) ? out_off2 : out_off;
    const bool do_head  = (HEAD_N > 0) && (bu == 0) && (hwp != nullptr);

    #pragma unroll
    for (int i = 0; i < 4; i++) {
        int idx = t + i * 512, row = idx >> 5, c = idx & 31;
        float4 v = reinterpret_cast<const float4*>(hbi + (size_t)(b0 + row) * 256)[c];
        *reinterpret_cast<float4*>(&hAs[row * 264 + c * 8]) = v;
    }
    if (do_head)
        for (int i = t; i < HEAD_N * 256; i += 512) hws[i] = hwp[i];
    __syncthreads();

    const int w = t >> 6, L = t & 63, q = L >> 4, ln = L & 15;
    const int m0 = (w & 3) * 16;
    const int U = bu * 32 + (w >> 2) * 16;
    const int unit = U + ln;

    bf16x8 a[8];
    #pragma unroll
    for (int kk = 0; kk < 8; kk++)
        a[kk] = *reinterpret_cast<const bf16x8*>(&hAs[(m0 + ln) * 264 + kk * 32 + q * 8]);

    f32x4v acc[4];
    #pragma unroll
    for (int g = 0; g < 4; g++) {
        f32x4v z = {0.f, 0.f, 0.f, 0.f};
        const ushort_t* wrow = Wb + (size_t)(g * 256 + unit) * 256 + q * 8;
        #pragma unroll
        for (int kk = 0; kk < 8; kk++) {
            bf16x8 bv = *reinterpret_cast<const bf16x8*>(wrow + kk * 32);
            z = __builtin_amdgcn_mfma_f32_16x16x32_bf16(a[kk], bv, z, 0, 0, 0);
        }
        acc[g] = z;
    }

    #pragma unroll
    for (int r = 0; r < 4; r++) {
        const int R = b0 + m0 + q * 4 + r;
        float pre[4];
        #pragma unroll
        for (int g = 0; g < 4; g++) {
            int col = g * 256 + unit;
            pre[g] = acc[g][r] + bf2f(obs_part[(size_t)R * 1024 + col]) + biasp[col];
        }
        if (SAMP == 1) {
            int si = sidx[R];
            #pragma unroll
            for (int g = 0; g < 4; g++) pre[g] += samp_rows[si * 1024 + g * 256 + unit];
        }
        if (SAMP == 2) {
            #pragma unroll
            for (int k = 0; k < 16; k++) {
                float e = rp0_emb[(size_t)R * 16 + k];
                #pragma unroll
                for (int g = 0; g < 4; g++) pre[g] += e * WsampT[k * 1024 + g * 256 + unit];
            }
        }
        float ci = cip[(size_t)R * 256 + unit];
        float c2 = sigf(pre[1]) * ci + sigf(pre[0]) * tanh_fast(pre[2]);
        float hv = sigf(pre[3]) * tanh_fast(c2);
        cop[(size_t)R * 256 + unit] = c2;
        hbo[(size_t)R * 256 + unit] = f2bf(hv);
    }

    if (do_head) {
        const int row = t >> 3, seg = t & 7;
        float part[3] = {0.f, 0.f, 0.f};
        #pragma unroll
        for (int j = 0; j < 4; j++) {
            uint4 v = *reinterpret_cast<const uint4*>(&hAs[row * 264 + seg * 32 + j * 8]);
            uint_t dw[4] = {v.x, v.y, v.z, v.w};
            #pragma unroll
            for (int d = 0; d < 4; d++) {
                float f0 = __uint_as_float(dw[d] << 16);
                float f1 = __uint_as_float(dw[d] & 0xffff0000u);
                int k = seg * 32 + j * 8 + d * 2;
                #pragma unroll
                for (int n = 0; n < HEAD_N; n++)
                    part[n] += f0 * hws[n * 256 + k] + f1 * hws[n * 256 + k + 1];
            }
        }
        #pragma unroll
        for (int n = 0; n < HEAD_N; n++) red[(row * 8 + seg) * 3 + n] = part[n];
        __syncthreads();
        if (t < 64) {
            #pragma unroll
            for (int n = 0; n < HEAD_N; n++) {
                float s = head_b[n];
                #pragma unroll
                for (int p = 0; p < 8; p++) s += red[(t * 8 + p) * 3 + n];
                out[(size_t)(b0 + t) * OUT_W + ooff + n] = s;
            }
        }
    }
}

// ---------------------------------------------------------------------------
// rp head: out[:, off:off+2] = rp[:, :2] + exp(rp[:, 2:]) * eps, from hb.
// ---------------------------------------------------------------------------
__global__ __launch_bounds__(256) void rp_head(
    const ushort_t* __restrict__ hb, const float* __restrict__ head_w,
    const float* __restrict__ head_b, const float* __restrict__ eps,
    float* __restrict__ out, int out_off, float* __restrict__ rp_store)
{
    __shared__ float hw[1024];
    __shared__ float red[64 * 4 * 4];
    const int t = threadIdx.x;
    const int b0 = blockIdx.x * 64;
    for (int i = t; i < 1024; i += 256) hw[i] = head_w[i];
    __syncthreads();
    const int r = t >> 2, p = t & 3;
    {
        const int R = b0 + r;
        float part[4] = {0.f, 0.f, 0.f, 0.f};
        const ushort_t* hr = hb + (size_t)R * 256 + p * 64;
        #pragma unroll
        for (int j = 0; j < 8; j++) {
            uint4 v = *reinterpret_cast<const uint4*>(hr + j * 8);
            uint_t dw[4] = {v.x, v.y, v.z, v.w};
            #pragma unroll
            for (int d = 0; d < 4; d++) {
                float f0 = __uint_as_float(dw[d] << 16);
                float f1 = __uint_as_float(dw[d] & 0xffff0000u);
                int k = p * 64 + j * 8 + d * 2;
                #pragma unroll
                for (int n = 0; n < 4; n++)
                    part[n] += f0 * hw[n * 256 + k] + f1 * hw[n * 256 + k + 1];
            }
        }
        #pragma unroll
        for (int n = 0; n < 4; n++) red[(r * 4 + p) * 4 + n] = part[n];
    }
    __syncthreads();
    if (t < 64) {
        const int R = b0 + t;
        float s[4];
        #pragma unroll
        for (int n = 0; n < 4; n++) {
            float v = head_b[n];
            #pragma unroll
            for (int p2 = 0; p2 < 4; p2++) v += red[(t * 4 + p2) * 4 + n];
            s[n] = v;
        }
        float v0 = s[0] + __expf(s[2]) * eps[(size_t)R * 2 + 0];
        float v1 = s[1] + __expf(s[3]) * eps[(size_t)R * 2 + 1];
        out[(size_t)R * OUT_W + out_off + 0] = v0;
        out[(size_t)R * OUT_W + out_off + 1] = v1;
        if (rp_store) {
            rp_store[(size_t)R * 2 + 0] = v0;
            rp_store[(size_t)R * 2 + 1] = v1;
        }
    }
}

// ---------------------------------------------------------------------------
// MLP: rp0 (B x 2) -> 100 -> 100 -> rp0_emb (B x 16)
// ---------------------------------------------------------------------------
__global__ __launch_bounds__(128) void mlp_kernel(
    const float* __restrict__ rp0, const float* __restrict__ w1,
    const float* __restrict__ b1, const float* __restrict__ w2t,
    const float* __restrict__ b2, const float* __restrict__ w3t,
    const float* __restrict__ b3, float* __restrict__ emb)
{
    __shared__ float z1[100], z2[100];
    int row = blockIdx.x, t = threadIdx.x;
    float r0 = rp0[(size_t)row * 2], r1 = rp0[(size_t)row * 2 + 1];
    if (t < 100) z1[t] = tanh_fast(b1[t] + w1[t * 2] * r0 + w1[t * 2 + 1] * r1);
    __syncthreads();
    if (t < 100) {
        float s = b2[t];
        for (int k = 0; k < 100; k++) s += w2t[k * 100 + t] * z1[k];
        z2[t] = tanh_fast(s);
    }
    __syncthreads();
    if (t < 16) {
        float s = b3[t];
        for (int k = 0; k < 100; k++) s += w3t[k * 16 + t] * z2[k];
        emb[(size_t)row * 16 + t] = s;
    }
}

// ---------------------------------------------------------------------------
extern "C" void kernel_launch(void* const* d_in, const int* in_sizes, int n_in,
                              void* d_out, int out_size, void* d_ws, size_t ws_size,
                              hipStream_t stream)
{
    const float* obs        = (const float*)d_in[0];
    const int*   program_id = (const int*)d_in[1];
    const int*   shape_id   = (const int*)d_in[2];
    const int*   shape_id_0 = (const int*)d_in[3];
    const int*   shape_id_1 = (const int*)d_in[4];
    const float* eps_rp     = (const float*)d_in[5];
    const float* eps_rp0    = (const float*)d_in[6];
    const float* eps_rp1    = (const float*)d_in[7];
    const float* conv1_w    = (const float*)d_in[8];
    const float* conv1_b    = (const float*)d_in[9];
    const float* conv2_w    = (const float*)d_in[10];
    const float* conv2_b    = (const float*)d_in[11];
    const float* mlp_w1     = (const float*)d_in[12];
    const float* mlp_b1     = (const float*)d_in[13];
    const float* mlp_w2     = (const float*)d_in[14];
    const float* mlp_b2     = (const float*)d_in[15];
    const float* mlp_w3     = (const float*)d_in[16];
    const float* mlp_b3     = (const float*)d_in[17];
    const float* W_ih       = (const float*)d_in[18];
    const float* b_ih       = (const float*)d_in[19];
    const float* W_hh       = (const float*)d_in[20];
    const float* b_hh       = (const float*)d_in[21];
    const float* addr_emb   = (const float*)d_in[22];
    const float* pid_emb    = (const float*)d_in[23];
    const float* sid_emb    = (const float*)d_in[24];
    const float* pid_ext_w  = (const float*)d_in[25];
    const float* pid_ext_b  = (const float*)d_in[26];
    const float* sid_ext_w  = (const float*)d_in[27];
    const float* sid_ext_b  = (const float*)d_in[28];
    const float* rp_ext_w   = (const float*)d_in[29];
    const float* rp_ext_b   = (const float*)d_in[30];
    float* out = (float*)d_out;

    // workspace layout (float slots, 16B-aligned chunks)
    float* ws = (float*)d_ws;
    size_t off = 0;
    float* W_ih_T   = ws + off; off += 432 * 1024;              // fp32
    ushort_t* Wb    = (ushort_t*)(ws + off); off += 131072;     // bf16 1024x256
    float* bias_all = ws + off; off += 7 * 1024;
    float* pid_rows = ws + off; off += 3 * 1024;
    float* sid_rows = ws + off; off += 2 * 1024;
    ushort_t* obs_emb_b = (ushort_t*)(ws + off); off += (size_t)BATCH * AK / 2;  // bf16 Bx448
    ushort_t* Wobs_b    = (ushort_t*)(ws + off); off += (size_t)1024 * AK / 2;   // bf16 1024x448
    ushort_t* obs_part = (ushort_t*)(ws + off); off += (size_t)BATCH * 512;  // bf16 Bx1024
    ushort_t* hb0 = (ushort_t*)(ws + off); off += (size_t)BATCH * 128;      // bf16 Bx256
    ushort_t* hbA = (ushort_t*)(ws + off); off += (size_t)BATCH * 128;
    ushort_t* hbB = (ushort_t*)(ws + off); off += (size_t)BATCH * 128;
    ushort_t* hbC = (ushort_t*)(ws + off); off += (size_t)BATCH * 128;
    ushort_t* hbA2 = (ushort_t*)(ws + off); off += (size_t)BATCH * 128;
    ushort_t* hbB2 = (ushort_t*)(ws + off); off += (size_t)BATCH * 128;
    float* c0 = ws + off; off += (size_t)BATCH * 256;
    float* cA = ws + off; off += (size_t)BATCH * 256;
    float* cB = ws + off; off += (size_t)BATCH * 256;
    float* cC = ws + off; off += (size_t)BATCH * 256;
    float* cD = ws + off; off += (size_t)BATCH * 256;   // dump for terminal c
    float* cA2 = ws + off; off += (size_t)BATCH * 256;
    float* rp0      = ws + off; off += (size_t)BATCH * 2;
    float* rp0_emb  = ws + off; off += (size_t)BATCH * 16;
    float* w2t = ws + off; off += 10000;
    float* w3t = ws + off; off += 1600;
    float* w1p = ws + off; off += 384;
    ushort_t* Btg = (ushort_t*)(ws + off); off += 2304;  // 4608 bf16
    float* WsampT = W_ih_T + (size_t)400 * 1024;  // rows 400..415 of W_ih_T (fp32)

    prep_kernel<<<140, 256, 0, stream>>>(W_ih, W_hh, b_ih, b_hh, addr_emb,
                                         pid_emb, sid_emb, mlp_w2, mlp_w3,
                                         conv1_w, conv1_b, conv2_w,
                                         W_ih_T, Wb, bias_all, pid_rows,
                                         sid_rows, w2t, w3t, w1p, Btg, Wobs_b);
    conv_kernel<<<BATCH, 512, 0, stream>>>(obs, w1p, Btg, conv2_b, obs_emb_b);
    obs_gemm<<<512, 256, 0, stream>>>(obs_emb_b, Wobs_b, obs_part);

    // step0 (aid 0): h=c=0 -> hb0, c0 (pid head on h0 folded into step1)
    step0_ew<<<BATCH, 256, 0, stream>>>(obs_part, bias_all + 0 * 1024, c0, hb0);

    // merged step1 (aid 1, head pid on h0 -> cols 0..2) + step1b (aid 2, no head)
    lstm_mfma<1, 3, 1><<<1024, 512, 0, stream>>>(
        hb0, c0, hbA, cA, obs_part, bias_all + 1 * 1024,
        pid_rows, program_id, nullptr, nullptr, Wb,
        pid_ext_w, pid_ext_b, out, 0,
        hb0, c0, hbA2, cA2, bias_all + 3 * 1024, program_id, nullptr, 0);
    // merged step2 (aid 4, head sid on h1 -> cols 3..4) + step2b (aid 3, head sid0 on h1b -> cols 7..8)
    lstm_mfma<1, 2, 1><<<1024, 512, 0, stream>>>(
        hbA, cA, hbB, cD, obs_part, bias_all + 2 * 1024,
        sid_rows, shape_id, nullptr, nullptr, Wb,
        sid_ext_w, sid_ext_b, out, 3,
        hbA2, cA2, hbB2, cB, bias_all + 4 * 1024, shape_id_0, sid_ext_w, 7);
    // rp_b0 head on h2 (hbB) -> cols 5..6
    rp_head<<<64, 256, 0, stream>>>(hbB, rp_ext_w, rp_ext_b, eps_rp, out, 5, nullptr);
    // step3b (aid 5): hbB2,cB -> hbC,cC; samp sid[shape_id_1]; head = sid1(2) on h2b -> cols 9..10
    lstm_mfma<1, 2, 0><<<512, 512, 0, stream>>>(
        hbB2, cB, hbC, cC, obs_part, bias_all + 5 * 1024,
        sid_rows, shape_id_1, nullptr, nullptr, Wb,
        sid_ext_w, sid_ext_b, out, 9,
        nullptr, nullptr, nullptr, nullptr, nullptr, nullptr, nullptr, 0);
    // rp0 head on h3b (hbC) -> cols 11..12, store rp0
    rp_head<<<64, 256, 0, stream>>>(hbC, rp_ext_w, rp_ext_b, eps_rp0, out, 11, rp0);
    mlp_kernel<<<BATCH, 128, 0, stream>>>(rp0, mlp_w1, mlp_b1, w2t, mlp_b2,
                                          w3t, mlp_b3, rp0_emb);
    // step4b (aid 6): hbC,cC -> hbB,cD; samp = rp0_emb @ WsampT; no head
    lstm_mfma<2, 0, 0><<<512, 512, 0, stream>>>(
        hbC, cC, hbB, cD, obs_part, bias_all + 6 * 1024,
        nullptr, nullptr, rp0_emb, WsampT, Wb,
        nullptr, nullptr, out, 0,
        nullptr, nullptr, nullptr, nullptr, nullptr, nullptr, nullptr, 0);
    // rp1 head on h4b (hbB) -> cols 13..14
    rp_head<<<64, 256, 0, stream>>>(hbB, rp_ext_w, rp_ext_b, eps_rp1, out, 13, nullptr);
}

// Round 4
// 487.554 us; speedup vs baseline: 1.0613x; 1.0613x over previous
//
#include <hip/hip_runtime.h>
#include <hip/hip_bf16.h>
#include <math.h>

#define BATCH 4096
#define HID 256
#define OUT_W 15
#define AK 448   // padded K for obs GEMM (400 valid + 48 zeros)

typedef unsigned short ushort_t;
typedef unsigned int uint_t;

using bf16x8 = __attribute__((ext_vector_type(8))) short;
using f32x4v = __attribute__((ext_vector_type(4))) float;

__device__ __forceinline__ float sigf(float x) { return 1.0f / (1.0f + __expf(-x)); }
__device__ __forceinline__ float tanh_fast(float x) { return 1.0f - 2.0f / (__expf(2.0f * x) + 1.0f); }
__device__ __forceinline__ float bf2f(ushort_t u) { return __uint_as_float(((uint_t)u) << 16); }
__device__ __forceinline__ ushort_t f2bf(float x) {
    uint_t b = __float_as_uint(x);
    return (ushort_t)((b + 0x7fffu + ((b >> 16) & 1u)) >> 16);
}

// ---------------------------------------------------------------------------
// Prep (44 blocks): WsampT tile of W_ih_T (only k 384..447 -> rows 400..415
// consumed), per-step biases, samp tables, mlp transposes, conv packs,
// W_hh -> bf16 [n][k], W_obs -> bf16 [col][448].
// ---------------------------------------------------------------------------
__global__ __launch_bounds__(256) void prep_kernel(
    const float* __restrict__ W_ih, const float* __restrict__ W_hh,
    const float* __restrict__ b_ih, const float* __restrict__ b_hh,
    const float* __restrict__ addr_emb, const float* __restrict__ pid_emb,
    const float* __restrict__ sid_emb,
    const float* __restrict__ mlp_w2, const float* __restrict__ mlp_w3,
    const float* __restrict__ conv1_w, const float* __restrict__ conv1_b,
    const float* __restrict__ conv2_w,
    float* __restrict__ W_ih_T, ushort_t* __restrict__ Wb,
    float* __restrict__ bias_all, float* __restrict__ pid_rows,
    float* __restrict__ sid_rows, float* __restrict__ w2t, float* __restrict__ w3t,
    float* __restrict__ w1p, ushort_t* __restrict__ Btg,
    ushort_t* __restrict__ Wobs_b)
{
    int blk = blockIdx.x, t = threadIdx.x;
    if (blk < 16) {
        // W_ih tile (64 cols j0, k 384..447) -> W_ih_T (WsampT source)
        __shared__ float tile[64][65];
        int j0 = blk * 64;
        int k0 = 384;
        for (int i = t; i < 4096; i += 256) {
            int r = i >> 6, c = i & 63;
            int k = k0 + c;
            tile[r][c] = (k < 432) ? W_ih[(size_t)(j0 + r) * 432 + k] : 0.f;
        }
        __syncthreads();
        for (int i = t; i < 4096; i += 256) {
            int r = i >> 6, c = i & 63;
            int k = k0 + r;
            if (k < 432) W_ih_T[(size_t)k * 1024 + j0 + c] = tile[c][r];
        }
    } else if (blk == 16) {
        const int aids[7] = {0, 1, 4, 2, 3, 5, 6};
        for (int s = 0; s < 7; s++) {
            int aid = aids[s];
            for (int j = t; j < 1024; j += 256) {
                float v = b_ih[j] + b_hh[j];
                #pragma unroll
                for (int k = 0; k < 16; k++)
                    v += addr_emb[aid * 16 + k] * W_ih[(size_t)j * 432 + 416 + k];
                bias_all[s * 1024 + j] = v;
            }
        }
    } else if (blk == 17) {
        for (int p = 0; p < 3; p++)
            for (int j = t; j < 1024; j += 256) {
                float v = 0.f;
                #pragma unroll
                for (int k = 0; k < 16; k++)
                    v += pid_emb[p * 16 + k] * W_ih[(size_t)j * 432 + 400 + k];
                pid_rows[p * 1024 + j] = v;
            }
        for (int p = 0; p < 2; p++)
            for (int j = t; j < 1024; j += 256) {
                float v = 0.f;
                #pragma unroll
                for (int k = 0; k < 16; k++)
                    v += sid_emb[p * 16 + k] * W_ih[(size_t)j * 432 + 400 + k];
                sid_rows[p * 1024 + j] = v;
            }
    } else if (blk == 18) {
        for (int i = t; i < 10000; i += 256) {
            int o = i / 100, k = i % 100;
            w2t[k * 100 + o] = mlp_w2[i];
        }
        for (int i = t; i < 1600; i += 256) {
            int o = i / 100, k = i % 100;
            w3t[k * 16 + o] = mlp_w3[i];
        }
    } else if (blk == 19) {
        for (int i = t; i < 384; i += 256) {
            int ic = i / 12, k = i % 12;
            float v = 0.f;
            if (k < 9) v = conv1_w[ic * 9 + k];
            else if (k == 9) v = conv1_b[ic];
            w1p[i] = v;
        }
        // Btg[(tap*16 + oc)*32 + ic] = conv2_w[(oc*32+ic)*9 + tap]
        for (int i = t; i < 4608; i += 256) {
            int tap = i >> 9;
            int rem = i & 511;
            int oc = rem >> 5, ic = rem & 31;
            Btg[i] = f2bf(conv2_w[(size_t)(oc * 32 + ic) * 9 + tap]);
        }
    } else if (blk < 28) {
        // W_hh (1024x256) fp32 -> bf16, same [n][k] layout
        int seg = blk - 20;  // 0..7
        for (int i = seg * 32768 + t; i < (seg + 1) * 32768; i += 256)
            Wb[i] = f2bf(W_hh[i]);
    } else {
        // W_obs rows of W_ih -> bf16 [col][448], k >= 400 zero
        int col0 = (blk - 28) * 64;  // 16 blocks x 64 cols
        for (int i = t; i < 64 * AK; i += 256) {
            int c = col0 + i / AK, k = i % AK;
            Wobs_b[(size_t)c * AK + k] = (k < 400) ? f2bf(W_ih[(size_t)c * 432 + k]) : (ushort_t)0;
        }
    }
}

// ---------------------------------------------------------------------------
// Conv encoder v6: two half-image phases over a 17-row ring buffer.
//   512 threads, LDS ~71 KB -> 2 blocks/CU.
//   sm2: row stride 72 floats, 16B-unit XOR swizzle (unit ^= (row>>1)&1)
//   -> kills the 4-way bank conflicts on conv1 patch reads (R2/R3's 19.4M).
//   conv1: thread (r,g,icq) computes row 16ph+r, cols 4g..4g+3, ic 8icq..;
//   packs 8 ic via v_cvt_pk_bf16_f32, one uint4 LDS write per position.
//   conv2: output rows 8ph..8ph+7, 1 row/wave, 9 tap-MFMAs.
//   Epilogue: pool -> LDS restage -> uint4 global stores (bf16, padded 448)
//   -> avoids the 2B-store write-allocate RMW blowup seen in R3.
// ---------------------------------------------------------------------------
#define CE_RS 640   // cE row stride in ushorts (16 pos * 40)
#define CO_RS 680   // cO row stride in ushorts (17 pos * 40)
#define SM2S 72     // sm2 row stride in floats (18 16B-units, XOR-swizzled)
__global__ __launch_bounds__(512, 4) void conv_kernel(
    const float* __restrict__ obs, const float* __restrict__ w1p,
    const ushort_t* __restrict__ Btg, const float* __restrict__ b2,
    ushort_t* __restrict__ obs_emb_b)
{
    __shared__ __align__(16) ushort_t cE[17 * CE_RS];  // 21760 B
    __shared__ __align__(16) ushort_t cO[17 * CO_RS];  // 23120 B
    __shared__ __align__(16) float c2s[16 * 260];      // 16640 B
    __shared__ __align__(16) float sm2[33 * SM2S];     // 9504 B
    __shared__ __align__(16) float w1s[384];           // 1536 B
    const int b = blockIdx.x, t = threadIdx.x;
    const float* og = obs + (size_t)b * 4096;

    const int w = t >> 6, L = t & 63, q = L >> 4, ln = L & 15;

    // conv2 B-fragments (same for every wave; L1-resident)
    bf16x8 Bv[9];
    #pragma unroll
    for (int tap = 0; tap < 9; tap++)
        Bv[tap] = *reinterpret_cast<const bf16x8*>(&Btg[(tap * 16 + ln) * 32 + q * 8]);

    // zero: cE buffer row 0 (c1 row -1), cO row 0, cO pos0 (col -1) rows 1..16
    {
        uint_t* zE = (uint_t*)cE;
        uint_t* zO = (uint_t*)cO;
        for (int i = t; i < CE_RS / 2; i += 512) zE[i] = 0;
        for (int i = t; i < CO_RS / 2; i += 512) zO[i] = 0;
        if (t < 320) {
            int row = (t / 20) + 1, d = t % 20;
            zO[row * (CO_RS / 2) + d] = 0;
        }
    }
    if (t < 96) ((float4*)w1s)[t] = ((const float4*)w1p)[t];
    if (t < 33) {
        int sw = (t >> 1) & 1;
        sm2[t * SM2S + sw * 4 + 3] = 0.f;  // logical col 3 (img col -1) = 0
    }

    // stage obs rows 32ph-1 .. 32ph+31 -> sm2 rows 0..32 (img col j at 4+j,
    // 16B-unit swizzle: logical unit u stored at u^((row>>1)&1))
    auto stage_obs = [&](int ph) {
        for (int i = t; i < 33 * 16; i += 512) {
            int row = i >> 4, c4 = i & 15;
            int sw = (row >> 1) & 1;
            int orow = 32 * ph - 1 + row;
            float4 v = float4{0.f, 0.f, 0.f, 0.f};
            if (orow >= 0) v = ((const float4*)(og + (size_t)orow * 64))[c4];
            *(float4*)&sm2[row * SM2S + ((1 + c4) ^ sw) * 4] = v;
        }
    };

    // conv1 phase: thread (r = t>>5, g = (t>>2)&7, icq = t&3) computes
    // c1 row 16ph+r, cols 4g..4g+3, ics 8icq..8icq+7.
    auto conv1_phase = [&](int ph) {
        const int r = t >> 5, g = (t >> 2) & 7, icq = t & 3;
        const int brow = ph ? r : (r + 1);
        // Pt[d][j] = obs[2*(16ph+r)-1+d][8g-4+j]; logical sm2 cols 8g..8g+11
        // = units 2g..2g+2 (phys unit = logical ^ sw(row)).
        float Pt[3][12];
        #pragma unroll
        for (int d = 0; d < 3; d++) {
            int row = 2 * r + d;
            int sw = (row >> 1) & 1;
            const float* base = &sm2[row * SM2S];
            #pragma unroll
            for (int j4 = 0; j4 < 3; j4++) {
                float4 v = *(const float4*)(base + ((2 * g + j4) ^ sw) * 4);
                Pt[d][j4 * 4 + 0] = v.x; Pt[d][j4 * 4 + 1] = v.y;
                Pt[d][j4 * 4 + 2] = v.z; Pt[d][j4 * 4 + 3] = v.w;
            }
        }
        uint_t pk[4][4];  // [pos][4 dwords = 8 ic bf16]
        #pragma unroll
        for (int ih = 0; ih < 2; ih++) {
            float W[4][10];
            #pragma unroll
            for (int i = 0; i < 4; i++) {
                const float* qw = &w1s[(icq * 8 + ih * 4 + i) * 12];
                float4 qa = *(const float4*)qw;
                float4 qb = *(const float4*)(qw + 4);
                float2 qc = *(const float2*)(qw + 8);
                W[i][0] = qa.x; W[i][1] = qa.y; W[i][2] = qa.z; W[i][3] = qa.w;
                W[i][4] = qb.x; W[i][5] = qb.y; W[i][6] = qb.z; W[i][7] = qb.w;
                W[i][8] = qc.x; W[i][9] = qc.y;
            }
            #pragma unroll
            for (int p = 0; p < 4; p++) {
                float sv[4];
                #pragma unroll
                for (int i = 0; i < 4; i++) {
                    float s = W[i][9];
                    #pragma unroll
                    for (int d = 0; d < 3; d++)
                        #pragma unroll
                        for (int dx = 0; dx < 3; dx++)
                            s += W[i][d * 3 + dx] * Pt[d][2 * p + 3 + dx];
                    sv[i] = fmaxf(s, 0.f);
                }
                uint_t w0, w1;
                asm("v_cvt_pk_bf16_f32 %0, %1, %2" : "=v"(w0) : "v"(sv[0]), "v"(sv[1]));
                asm("v_cvt_pk_bf16_f32 %0, %1, %2" : "=v"(w1) : "v"(sv[2]), "v"(sv[3]));
                pk[p][ih * 2 + 0] = w0;
                pk[p][ih * 2 + 1] = w1;
            }
        }
        #pragma unroll
        for (int p = 0; p < 4; p++) {
            int c = 4 * g + p;
            ushort_t* dst = (c & 1)
                ? &cO[brow * CO_RS + ((c + 1) >> 1) * 40 + icq * 8]
                : &cE[brow * CE_RS + (c >> 1) * 40 + icq * 8];
            *(uint4*)dst = uint4{pk[p][0], pk[p][1], pk[p][2], pk[p][3]};
        }
    };

    // conv2 phase: wave w -> output row y = 8ph+w; 9 tap-MFMAs; epilogue to c2s
    auto conv2_phase = [&](int ph) {
        const int y = 8 * ph + w;
        f32x4v C = {0.f, 0.f, 0.f, 0.f};
        #pragma unroll
        for (int dy = 0; dy < 3; dy++) {
            int br = 2 * y + dy;          // (c1row+1); c1row = 2y-1+dy
            if (br >= 17) br -= 17;
            bf16x8 a0 = *reinterpret_cast<const bf16x8*>(&cO[br * CO_RS + ln * 40 + q * 8]);        // dx=0: col 2m-1
            bf16x8 a1 = *reinterpret_cast<const bf16x8*>(&cE[br * CE_RS + ln * 40 + q * 8]);        // dx=1: col 2m
            bf16x8 a2 = *reinterpret_cast<const bf16x8*>(&cO[br * CO_RS + (ln + 1) * 40 + q * 8]);  // dx=2: col 2m+1
            C = __builtin_amdgcn_mfma_f32_16x16x32_bf16(a0, Bv[dy * 3 + 0], C, 0, 0, 0);
            C = __builtin_amdgcn_mfma_f32_16x16x32_bf16(a1, Bv[dy * 3 + 1], C, 0, 0, 0);
            C = __builtin_amdgcn_mfma_f32_16x16x32_bf16(a2, Bv[dy * 3 + 2], C, 0, 0, 0);
        }
        float bb2 = b2[ln];
        float4 o;
        o.x = fmaxf(C[0] + bb2, 0.f);
        o.y = fmaxf(C[1] + bb2, 0.f);
        o.z = fmaxf(C[2] + bb2, 0.f);
        o.w = fmaxf(C[3] + bb2, 0.f);
        *(float4*)&c2s[ln * 260 + y * 16 + q * 4] = o;  // oc=ln, x=q*4+r
    };

    stage_obs(0);
    __syncthreads();
    conv1_phase(0);            // writes buffer rows 1..16 (c1 rows 0..15)
    __syncthreads();
    stage_obs(1);              // global loads overlap phase-0 MFMAs
    conv2_phase(0);            // reads rows 0..16; c2 rows 0..7
    __syncthreads();
    conv1_phase(1);            // writes buffer rows 0..15 (c1 rows 16..31)
    __syncthreads();
    conv2_phase(1);            // c2 rows 8..15
    __syncthreads();

    // pool 3x3 stride 3 -> LDS restage -> vectorized bf16 store (448 padded)
    ushort_t* ew = (ushort_t*)w1s;   // 896 B needed; w1s dead after conv1
    if (t < 400) {
        int c = t / 25, rem = t % 25, py = rem / 5, px = rem % 5;
        float s = 0.f;
        #pragma unroll
        for (int dy = 0; dy < 3; dy++)
            #pragma unroll
            for (int dx = 0; dx < 3; dx++)
                s += c2s[c * 260 + (3 * py + dy) * 16 + 3 * px + dx];
        ew[t] = f2bf(s * (1.f / 9.f));
    } else if (t < AK) {
        ew[t] = 0;
    }
    __syncthreads();
    if (t < 56)
        ((uint4*)(obs_emb_b + (size_t)b * AK))[t] = ((const uint4*)ew)[t];
}

// ---------------------------------------------------------------------------
// obs_part (bf16) = obs_emb_b (B x 448 bf16) @ Wobs_b.T -> (B x 1024), MFMA.
// Store restaged through LDS -> full-line uint4 global writes.
// ---------------------------------------------------------------------------
__global__ __launch_bounds__(256) void obs_gemm(
    const ushort_t* __restrict__ Ab, const ushort_t* __restrict__ Wob,
    ushort_t* __restrict__ outp)
{
    __shared__ __align__(16) ushort_t As[64 * 72];   // 9216 B
    __shared__ __align__(16) ushort_t ob[64 * 132];  // 16896 B
    const int t = threadIdx.x;
    const int bm = blockIdx.x & 63, bu = blockIdx.x >> 6;
    const int b0 = bm * 64, n0 = bu * 128;
    const int w = t >> 6, L = t & 63, q = L >> 4, ln = L & 15;
    const int m0 = w * 16;

    f32x4v acc[8];
    #pragma unroll
    for (int i = 0; i < 8; i++) acc[i] = f32x4v{0.f, 0.f, 0.f, 0.f};

    for (int kc = 0; kc < 7; kc++) {
        // stage A chunk: 64 rows x 64 k (bf16)
        #pragma unroll
        for (int ii = 0; ii < 2; ii++) {
            int i = t + ii * 256;
            int row = i >> 3, c8 = i & 7;
            *(uint4*)&As[row * 72 + c8 * 8] =
                *(const uint4*)&Ab[(size_t)(b0 + row) * AK + kc * 64 + c8 * 8];
        }
        __syncthreads();
        bf16x8 a[2];
        #pragma unroll
        for (int ks = 0; ks < 2; ks++)
            a[ks] = *reinterpret_cast<const bf16x8*>(&As[(m0 + ln) * 72 + ks * 32 + q * 8]);
        #pragma unroll
        for (int ct = 0; ct < 8; ct++) {
            const ushort_t* wr = Wob + (size_t)(n0 + ct * 16 + ln) * AK + kc * 64 + q * 8;
            bf16x8 bv0 = *reinterpret_cast<const bf16x8*>(wr);
            bf16x8 bv1 = *reinterpret_cast<const bf16x8*>(wr + 32);
            acc[ct] = __builtin_amdgcn_mfma_f32_16x16x32_bf16(a[0], bv0, acc[ct], 0, 0, 0);
            acc[ct] = __builtin_amdgcn_mfma_f32_16x16x32_bf16(a[1], bv1, acc[ct], 0, 0, 0);
        }
        __syncthreads();
    }
    // restage C tile in LDS (bf16) then vectorized store
    #pragma unroll
    for (int ct = 0; ct < 8; ct++)
        #pragma unroll
        for (int j = 0; j < 4; j++)
            ob[(m0 + q * 4 + j) * 132 + ct * 16 + ln] = f2bf(acc[ct][j]);
    __syncthreads();
    #pragma unroll
    for (int p2 = 0; p2 < 4; p2++) {
        int idx = t + p2 * 256;
        int row = idx >> 4, c8 = idx & 15;
        uint4 v = *(const uint4*)&ob[row * 132 + c8 * 8];
        *(uint4*)&outp[(size_t)(b0 + row) * 1024 + n0 + c8 * 8] = v;
    }
}

// ---------------------------------------------------------------------------
// step0 elementwise: h=c=0 -> c0 (fp32), hb0 (bf16). pre = obs_part + bias0.
// ---------------------------------------------------------------------------
__global__ __launch_bounds__(256) void step0_ew(
    const ushort_t* __restrict__ obs_part, const float* __restrict__ bias_s,
    float* __restrict__ c_out, ushort_t* __restrict__ hb_out)
{
    const int R = blockIdx.x, u = threadIdx.x;
    float pre[4];
    #pragma unroll
    for (int g = 0; g < 4; g++)
        pre[g] = bf2f(obs_part[(size_t)R * 1024 + g * 256 + u]) + bias_s[g * 256 + u];
    float c2 = sigf(pre[0]) * tanh_fast(pre[2]);
    float hv = sigf(pre[3]) * tanh_fast(c2);
    c_out[(size_t)R * 256 + u] = c2;
    hb_out[(size_t)R * 256 + u] = f2bf(hv);
}

// ---------------------------------------------------------------------------
// MFMA LSTM step v2: short critical path.
//   - A-fragments loaded DIRECTLY from global (no hAs staging / barrier).
//   - obs_part slice (64x128 bf16) and c_in slice (64x32 f32) cooperatively
//     staged into conflict-free-padded LDS; latency hides under MFMAs.
//   - epilogue reads LDS, writes results back in-place (ps g0-slot / cs);
//     final phase stores full 64-256B segments (no 2B-store RMW).
//   DUAL=1: 1024 blocks, two independent steps in one launch.
// ---------------------------------------------------------------------------
template <int SAMP, int HEAD_N, int DUAL>
__global__ __launch_bounds__(512, 4) void lstm_mfma(
    const ushort_t* __restrict__ hb_in, const float* __restrict__ c_in,
    ushort_t* __restrict__ hb_out, float* __restrict__ c_out,
    const ushort_t* __restrict__ obs_part, const float* __restrict__ bias_s,
    const float* __restrict__ samp_rows, const int* __restrict__ samp_idx,
    const float* __restrict__ rp0_emb, const float* __restrict__ WsampT,
    const ushort_t* __restrict__ Wb,
    const float* __restrict__ head_w, const float* __restrict__ head_b,
    float* __restrict__ out, int out_off,
    const ushort_t* __restrict__ hb_in2, const float* __restrict__ c_in2,
    ushort_t* __restrict__ hb_out2, float* __restrict__ c_out2,
    const float* __restrict__ bias_s2, const int* __restrict__ samp_idx2,
    const float* __restrict__ head_w2, int out_off2)
{
    constexpr int PS_B = 64 * 132 * 2;   // 16896
    constexpr int CS_B = 64 * 36 * 4;    // 9216
    constexpr int EX_B = (SAMP == 2) ? (16 * 132 * 4 + 64 * 20 * 4)   // wsmp + re
                                     : (3 * 256 * 4 + 64 * 8 * 3 * 4); // hws + red
    __shared__ __align__(16) char smem[PS_B + CS_B + EX_B];
    ushort_t* ps = (ushort_t*)smem;               // [64][132] bf16
    float* cs = (float*)(smem + PS_B);            // [64][36] f32
    float* hws = (float*)(smem + PS_B + CS_B);    // head weights
    float* red = (float*)(smem + PS_B + CS_B + 3 * 256 * 4);
    float* wsmp = (float*)(smem + PS_B + CS_B);   // [16][132] f32 (SAMP2)
    float* re = (float*)(smem + PS_B + CS_B + 16 * 132 * 4);  // [64][20]

    const int t = threadIdx.x;
    const int half  = DUAL ? (int)(blockIdx.x >> 9) : 0;
    const int inner = DUAL ? (int)(blockIdx.x & 511) : (int)blockIdx.x;
    const int bm = inner & 63, bu = inner >> 6;
    const int b0 = bm * 64;

    const ushort_t* hbi = (DUAL && half) ? hb_in2 : hb_in;
    const float* cip    = (DUAL && half) ? c_in2 : c_in;
    ushort_t* hbo       = (DUAL && half) ? hb_out2 : hb_out;
    float* cop          = (DUAL && half) ? c_out2 : c_out;
    const float* biasp  = (DUAL && half) ? bias_s2 : bias_s;
    const int* sidx     = (DUAL && half) ? samp_idx2 : samp_idx;
    const float* hwp    = (DUAL && half) ? head_w2 : head_w;
    const int ooff      = (DUAL && half) ? out_off2 : out_off;
    const bool do_head  = (HEAD_N > 0) && (bu == 0) && (hwp != nullptr);

    const int w = t >> 6, L = t & 63, q = L >> 4, ln = L & 15;
    const int m0 = (w & 3) * 16, wg = w >> 2;
    const int U0 = bu * 32;
    const int unit = U0 + wg * 16 + ln;

    // A fragments: direct global loads (hb L2-resident)
    bf16x8 a[8];
    {
        const ushort_t* arow = hbi + (size_t)(b0 + m0 + ln) * 256 + q * 8;
        #pragma unroll
        for (int kk = 0; kk < 8; kk++)
            a[kk] = *reinterpret_cast<const bf16x8*>(arow + kk * 32);
    }

    // cooperative staging (hidden under MFMAs)
    #pragma unroll
    for (int p = 0; p < 2; p++) {
        int idx = t + p * 512;
        int row = idx >> 4, c8 = idx & 15;
        int g = c8 >> 2, cc = (c8 & 3) * 8;
        uint4 v = *(const uint4*)&obs_part[(size_t)(b0 + row) * 1024 + g * 256 + U0 + cc];
        *(uint4*)&ps[row * 132 + c8 * 8] = v;
    }
    {
        int row = t >> 3, c4 = t & 7;
        float4 v = *(const float4*)&cip[(size_t)(b0 + row) * 256 + U0 + c4 * 4];
        *(float4*)&cs[row * 36 + c4 * 4] = v;
    }
    if (SAMP == 2) {
        int k = t >> 5, c4 = t & 31;
        float4 v = *(const float4*)&WsampT[(size_t)k * 1024 + ((c4 * 4) >> 5) * 256 + U0 + ((c4 * 4) & 31)];
        *(float4*)&wsmp[k * 132 + c4 * 4] = v;
        if (t < 256) {
            int row = t >> 2, d4 = t & 3;
            float4 e = *(const float4*)&rp0_emb[(size_t)(b0 + row) * 16 + d4 * 4];
            *(float4*)&re[row * 20 + d4 * 4] = e;
        }
    }
    if (do_head)
        for (int i = t; i < HEAD_N * 256; i += 512) hws[i] = hwp[i];

    // MFMA: 4 gates x 8 K-chunks
    f32x4v acc[4];
    #pragma unroll
    for (int g = 0; g < 4; g++) {
        f32x4v z = {0.f, 0.f, 0.f, 0.f};
        const ushort_t* wrow = Wb + (size_t)(g * 256 + unit) * 256 + q * 8;
        #pragma unroll
        for (int kk = 0; kk < 8; kk++) {
            bf16x8 bv = *reinterpret_cast<const bf16x8*>(wrow + kk * 32);
            z = __builtin_amdgcn_mfma_f32_16x16x32_bf16(a[kk], bv, z, 0, 0, 0);
        }
        acc[g] = z;
    }
    __syncthreads();   // staged data visible

    float bsv[4];
    #pragma unroll
    for (int g = 0; g < 4; g++) bsv[g] = biasp[g * 256 + unit];

    const int cc = wg * 16 + ln;
    #pragma unroll
    for (int r = 0; r < 4; r++) {
        const int row = m0 + q * 4 + r;
        const int R = b0 + row;
        float pre[4];
        #pragma unroll
        for (int g = 0; g < 4; g++)
            pre[g] = acc[g][r] + bf2f(ps[row * 132 + g * 32 + cc]) + bsv[g];
        if (SAMP == 1) {
            int si = sidx[R];
            #pragma unroll
            for (int g = 0; g < 4; g++) pre[g] += samp_rows[si * 1024 + g * 256 + unit];
        }
        if (SAMP == 2) {
            #pragma unroll
            for (int k = 0; k < 16; k++) {
                float e = re[row * 20 + k];
                #pragma unroll
                for (int g = 0; g < 4; g++) pre[g] += e * wsmp[k * 132 + g * 32 + cc];
            }
        }
        float ci = cs[row * 36 + cc];
        float c2 = sigf(pre[1]) * ci + sigf(pre[0]) * tanh_fast(pre[2]);
        float hv = sigf(pre[3]) * tanh_fast(c2);
        cs[row * 36 + cc] = c2;              // in-place (own cell)
        ps[row * 132 + cc] = f2bf(hv);       // g0 slot (own cell, already read)
    }
    __syncthreads();

    // vectorized stores
    {
        int row = t >> 3, c4 = t & 7;
        float4 v = *(const float4*)&cs[row * 36 + c4 * 4];
        *(float4*)&cop[(size_t)(b0 + row) * 256 + U0 + c4 * 4] = v;
    }
    if (t < 256) {
        int row = t >> 2, c8 = t & 3;
        uint4 v = *(const uint4*)&ps[row * 132 + c8 * 8];
        *(uint4*)&hbo[(size_t)(b0 + row) * 256 + U0 + c8 * 8] = v;
    }

    if (do_head) {
        const int row = t >> 3, seg = t & 7;
        const ushort_t* hrow = hbi + (size_t)(b0 + row) * 256 + seg * 32;
        float part[3] = {0.f, 0.f, 0.f};
        #pragma unroll
        for (int j = 0; j < 4; j++) {
            uint4 v = *(const uint4*)(hrow + j * 8);
            uint_t dw[4] = {v.x, v.y, v.z, v.w};
            #pragma unroll
            for (int d = 0; d < 4; d++) {
                float f0 = __uint_as_float(dw[d] << 16);
                float f1 = __uint_as_float(dw[d] & 0xffff0000u);
                int k = seg * 32 + j * 8 + d * 2;
                #pragma unroll
                for (int n = 0; n < HEAD_N; n++)
                    part[n] += f0 * hws[n * 256 + k] + f1 * hws[n * 256 + k + 1];
            }
        }
        #pragma unroll
        for (int n = 0; n < HEAD_N; n++) red[(row * 8 + seg) * 3 + n] = part[n];
        __syncthreads();
        if (t < 64) {
            #pragma unroll
            for (int n = 0; n < HEAD_N; n++) {
                float s = head_b[n];
                #pragma unroll
                for (int p = 0; p < 8; p++) s += red[(t * 8 + p) * 3 + n];
                out[(size_t)(b0 + t) * OUT_W + ooff + n] = s;
            }
        }
    }
}

// ---------------------------------------------------------------------------
// rp head: out[:, off:off+2] = rp[:, :2] + exp(rp[:, 2:]) * eps, from hb.
// ---------------------------------------------------------------------------
__global__ __launch_bounds__(256) void rp_head(
    const ushort_t* __restrict__ hb, const float* __restrict__ head_w,
    const float* __restrict__ head_b, const float* __restrict__ eps,
    float* __restrict__ out, int out_off, float* __restrict__ rp_store)
{
    __shared__ float hw[1024];
    __shared__ float red[64 * 4 * 4];
    const int t = threadIdx.x;
    const int b0 = blockIdx.x * 64;
    for (int i = t; i < 1024; i += 256) hw[i] = head_w[i];
    __syncthreads();
    const int r = t >> 2, p = t & 3;
    {
        const int R = b0 + r;
        float part[4] = {0.f, 0.f, 0.f, 0.f};
        const ushort_t* hr = hb + (size_t)R * 256 + p * 64;
        #pragma unroll
        for (int j = 0; j < 8; j++) {
            uint4 v = *reinterpret_cast<const uint4*>(hr + j * 8);
            uint_t dw[4] = {v.x, v.y, v.z, v.w};
            #pragma unroll
            for (int d = 0; d < 4; d++) {
                float f0 = __uint_as_float(dw[d] << 16);
                float f1 = __uint_as_float(dw[d] & 0xffff0000u);
                int k = p * 64 + j * 8 + d * 2;
                #pragma unroll
                for (int n = 0; n < 4; n++)
                    part[n] += f0 * hw[n * 256 + k] + f1 * hw[n * 256 + k + 1];
            }
        }
        #pragma unroll
        for (int n = 0; n < 4; n++) red[(r * 4 + p) * 4 + n] = part[n];
    }
    __syncthreads();
    if (t < 64) {
        const int R = b0 + t;
        float s[4];
        #pragma unroll
        for (int n = 0; n < 4; n++) {
            float v = head_b[n];
            #pragma unroll
            for (int p2 = 0; p2 < 4; p2++) v += red[(t * 4 + p2) * 4 + n];
            s[n] = v;
        }
        float v0 = s[0] + __expf(s[2]) * eps[(size_t)R * 2 + 0];
        float v1 = s[1] + __expf(s[3]) * eps[(size_t)R * 2 + 1];
        out[(size_t)R * OUT_W + out_off + 0] = v0;
        out[(size_t)R * OUT_W + out_off + 1] = v1;
        if (rp_store) {
            rp_store[(size_t)R * 2 + 0] = v0;
            rp_store[(size_t)R * 2 + 1] = v1;
        }
    }
}

// ---------------------------------------------------------------------------
// MLP: rp0 (B x 2) -> 100 -> 100 -> rp0_emb (B x 16)
// ---------------------------------------------------------------------------
__global__ __launch_bounds__(128) void mlp_kernel(
    const float* __restrict__ rp0, const float* __restrict__ w1,
    const float* __restrict__ b1, const float* __restrict__ w2t,
    const float* __restrict__ b2, const float* __restrict__ w3t,
    const float* __restrict__ b3, float* __restrict__ emb)
{
    __shared__ float z1[100], z2[100];
    int row = blockIdx.x, t = threadIdx.x;
    float r0 = rp0[(size_t)row * 2], r1 = rp0[(size_t)row * 2 + 1];
    if (t < 100) z1[t] = tanh_fast(b1[t] + w1[t * 2] * r0 + w1[t * 2 + 1] * r1);
    __syncthreads();
    if (t < 100) {
        float s = b2[t];
        for (int k = 0; k < 100; k++) s += w2t[k * 100 + t] * z1[k];
        z2[t] = tanh_fast(s);
    }
    __syncthreads();
    if (t < 16) {
        float s = b3[t];
        for (int k = 0; k < 100; k++) s += w3t[k * 16 + t] * z2[k];
        emb[(size_t)row * 16 + t] = s;
    }
}

// ---------------------------------------------------------------------------
extern "C" void kernel_launch(void* const* d_in, const int* in_sizes, int n_in,
                              void* d_out, int out_size, void* d_ws, size_t ws_size,
                              hipStream_t stream)
{
    const float* obs        = (const float*)d_in[0];
    const int*   program_id = (const int*)d_in[1];
    const int*   shape_id   = (const int*)d_in[2];
    const int*   shape_id_0 = (const int*)d_in[3];
    const int*   shape_id_1 = (const int*)d_in[4];
    const float* eps_rp     = (const float*)d_in[5];
    const float* eps_rp0    = (const float*)d_in[6];
    const float* eps_rp1    = (const float*)d_in[7];
    const float* conv1_w    = (const float*)d_in[8];
    const float* conv1_b    = (const float*)d_in[9];
    const float* conv2_w    = (const float*)d_in[10];
    const float* conv2_b    = (const float*)d_in[11];
    const float* mlp_w1     = (const float*)d_in[12];
    const float* mlp_b1     = (const float*)d_in[13];
    const float* mlp_w2     = (const float*)d_in[14];
    const float* mlp_b2     = (const float*)d_in[15];
    const float* mlp_w3     = (const float*)d_in[16];
    const float* mlp_b3     = (const float*)d_in[17];
    const float* W_ih       = (const float*)d_in[18];
    const float* b_ih       = (const float*)d_in[19];
    const float* W_hh       = (const float*)d_in[20];
    const float* b_hh       = (const float*)d_in[21];
    const float* addr_emb   = (const float*)d_in[22];
    const float* pid_emb    = (const float*)d_in[23];
    const float* sid_emb    = (const float*)d_in[24];
    const float* pid_ext_w  = (const float*)d_in[25];
    const float* pid_ext_b  = (const float*)d_in[26];
    const float* sid_ext_w  = (const float*)d_in[27];
    const float* sid_ext_b  = (const float*)d_in[28];
    const float* rp_ext_w   = (const float*)d_in[29];
    const float* rp_ext_b   = (const float*)d_in[30];
    float* out = (float*)d_out;

    // workspace layout (float slots, 16B-aligned chunks)
    float* ws = (float*)d_ws;
    size_t off = 0;
    float* W_ih_T   = ws + off; off += 432 * 1024;              // fp32
    ushort_t* Wb    = (ushort_t*)(ws + off); off += 131072;     // bf16 1024x256
    float* bias_all = ws + off; off += 7 * 1024;
    float* pid_rows = ws + off; off += 3 * 1024;
    float* sid_rows = ws + off; off += 2 * 1024;
    ushort_t* obs_emb_b = (ushort_t*)(ws + off); off += (size_t)BATCH * AK / 2;  // bf16 Bx448
    ushort_t* Wobs_b    = (ushort_t*)(ws + off); off += (size_t)1024 * AK / 2;   // bf16 1024x448
    ushort_t* obs_part = (ushort_t*)(ws + off); off += (size_t)BATCH * 512;  // bf16 Bx1024
    ushort_t* hb0 = (ushort_t*)(ws + off); off += (size_t)BATCH * 128;      // bf16 Bx256
    ushort_t* hbA = (ushort_t*)(ws + off); off += (size_t)BATCH * 128;
    ushort_t* hbB = (ushort_t*)(ws + off); off += (size_t)BATCH * 128;
    ushort_t* hbC = (ushort_t*)(ws + off); off += (size_t)BATCH * 128;
    ushort_t* hbA2 = (ushort_t*)(ws + off); off += (size_t)BATCH * 128;
    ushort_t* hbB2 = (ushort_t*)(ws + off); off += (size_t)BATCH * 128;
    float* c0 = ws + off; off += (size_t)BATCH * 256;
    float* cA = ws + off; off += (size_t)BATCH * 256;
    float* cB = ws + off; off += (size_t)BATCH * 256;
    float* cC = ws + off; off += (size_t)BATCH * 256;
    float* cD = ws + off; off += (size_t)BATCH * 256;   // dump for terminal c
    float* cA2 = ws + off; off += (size_t)BATCH * 256;
    float* rp0      = ws + off; off += (size_t)BATCH * 2;
    float* rp0_emb  = ws + off; off += (size_t)BATCH * 16;
    float* w2t = ws + off; off += 10000;
    float* w3t = ws + off; off += 1600;
    float* w1p = ws + off; off += 384;
    ushort_t* Btg = (ushort_t*)(ws + off); off += 2304;  // 4608 bf16
    float* WsampT = W_ih_T + (size_t)400 * 1024;  // rows 400..415 of W_ih_T (fp32)

    prep_kernel<<<44, 256, 0, stream>>>(W_ih, W_hh, b_ih, b_hh, addr_emb,
                                        pid_emb, sid_emb, mlp_w2, mlp_w3,
                                        conv1_w, conv1_b, conv2_w,
                                        W_ih_T, Wb, bias_all, pid_rows,
                                        sid_rows, w2t, w3t, w1p, Btg, Wobs_b);
    conv_kernel<<<BATCH, 512, 0, stream>>>(obs, w1p, Btg, conv2_b, obs_emb_b);
    obs_gemm<<<512, 256, 0, stream>>>(obs_emb_b, Wobs_b, obs_part);

    // step0 (aid 0): h=c=0 -> hb0, c0 (pid head on h0 folded into step1)
    step0_ew<<<BATCH, 256, 0, stream>>>(obs_part, bias_all + 0 * 1024, c0, hb0);

    // merged step1 (aid 1, head pid on h0 -> cols 0..2) + step1b (aid 2, no head)
    lstm_mfma<1, 3, 1><<<1024, 512, 0, stream>>>(
        hb0, c0, hbA, cA, obs_part, bias_all + 1 * 1024,
        pid_rows, program_id, nullptr, nullptr, Wb,
        pid_ext_w, pid_ext_b, out, 0,
        hb0, c0, hbA2, cA2, bias_all + 3 * 1024, program_id, nullptr, 0);
    // merged step2 (aid 4, head sid on h1 -> cols 3..4) + step2b (aid 3, head sid0 on h1b -> cols 7..8)
    lstm_mfma<1, 2, 1><<<1024, 512, 0, stream>>>(
        hbA, cA, hbB, cD, obs_part, bias_all + 2 * 1024,
        sid_rows, shape_id, nullptr, nullptr, Wb,
        sid_ext_w, sid_ext_b, out, 3,
        hbA2, cA2, hbB2, cB, bias_all + 4 * 1024, shape_id_0, sid_ext_w, 7);
    // rp_b0 head on h2 (hbB) -> cols 5..6
    rp_head<<<64, 256, 0, stream>>>(hbB, rp_ext_w, rp_ext_b, eps_rp, out, 5, nullptr);
    // step3b (aid 5): hbB2,cB -> hbC,cC; samp sid[shape_id_1]; head = sid1(2) on h2b -> cols 9..10
    lstm_mfma<1, 2, 0><<<512, 512, 0, stream>>>(
        hbB2, cB, hbC, cC, obs_part, bias_all + 5 * 1024,
        sid_rows, shape_id_1, nullptr, nullptr, Wb,
        sid_ext_w, sid_ext_b, out, 9,
        nullptr, nullptr, nullptr, nullptr, nullptr, nullptr, nullptr, 0);
    // rp0 head on h3b (hbC) -> cols 11..12, store rp0
    rp_head<<<64, 256, 0, stream>>>(hbC, rp_ext_w, rp_ext_b, eps_rp0, out, 11, rp0);
    mlp_kernel<<<BATCH, 128, 0, stream>>>(rp0, mlp_w1, mlp_b1, w2t, mlp_b2,
                                          w3t, mlp_b3, rp0_emb);
    // step4b (aid 6): hbC,cC -> hbB,cD; samp = rp0_emb @ WsampT; no head
    lstm_mfma<2, 0, 0><<<512, 512, 0, stream>>>(
        hbC, cC, hbB, cD, obs_part, bias_all + 6 * 1024,
        nullptr, nullptr, rp0_emb, WsampT, Wb,
        nullptr, nullptr, out, 0,
        nullptr, nullptr, nullptr, nullptr, nullptr, nullptr, nullptr, 0);
    // rp1 head on h4b (hbB) -> cols 13..14
    rp_head<<<64, 256, 0, stream>>>(hbB, rp_ext_w, rp_ext_b, eps_rp1, out, 13, nullptr);
}

// Round 5
// 465.446 us; speedup vs baseline: 1.1117x; 1.0475x over previous
//
#include <hip/hip_runtime.h>
#include <hip/hip_bf16.h>
#include <math.h>

#define BATCH 4096
#define HID 256
#define OUT_W 15
#define AK 448   // padded K for obs GEMM (400 valid + 48 zeros)

typedef unsigned short ushort_t;
typedef unsigned int uint_t;

using bf16x8 = __attribute__((ext_vector_type(8))) short;
using f32x4v = __attribute__((ext_vector_type(4))) float;

__device__ __forceinline__ float sigf(float x) { return 1.0f / (1.0f + __expf(-x)); }
__device__ __forceinline__ float tanh_fast(float x) { return 1.0f - 2.0f / (__expf(2.0f * x) + 1.0f); }
__device__ __forceinline__ float bf2f(ushort_t u) { return __uint_as_float(((uint_t)u) << 16); }
__device__ __forceinline__ ushort_t f2bf(float x) {
    uint_t b = __float_as_uint(x);
    return (ushort_t)((b + 0x7fffu + ((b >> 16) & 1u)) >> 16);
}

// ---------------------------------------------------------------------------
// Prep (44 blocks): WsampT tile of W_ih_T (only k 384..447 -> rows 400..415
// consumed), per-step biases, samp tables, mlp transposes, conv packs,
// W_hh -> bf16 [n][k], W_obs -> bf16 [col][448].
// ---------------------------------------------------------------------------
__global__ __launch_bounds__(256) void prep_kernel(
    const float* __restrict__ W_ih, const float* __restrict__ W_hh,
    const float* __restrict__ b_ih, const float* __restrict__ b_hh,
    const float* __restrict__ addr_emb, const float* __restrict__ pid_emb,
    const float* __restrict__ sid_emb,
    const float* __restrict__ mlp_w2, const float* __restrict__ mlp_w3,
    const float* __restrict__ conv1_w, const float* __restrict__ conv1_b,
    const float* __restrict__ conv2_w,
    float* __restrict__ W_ih_T, ushort_t* __restrict__ Wb,
    float* __restrict__ bias_all, float* __restrict__ pid_rows,
    float* __restrict__ sid_rows, float* __restrict__ w2t, float* __restrict__ w3t,
    float* __restrict__ w1p, ushort_t* __restrict__ Btg,
    ushort_t* __restrict__ Wobs_b)
{
    int blk = blockIdx.x, t = threadIdx.x;
    if (blk < 16) {
        // W_ih tile (64 cols j0, k 384..447) -> W_ih_T (WsampT source)
        __shared__ float tile[64][65];
        int j0 = blk * 64;
        int k0 = 384;
        for (int i = t; i < 4096; i += 256) {
            int r = i >> 6, c = i & 63;
            int k = k0 + c;
            tile[r][c] = (k < 432) ? W_ih[(size_t)(j0 + r) * 432 + k] : 0.f;
        }
        __syncthreads();
        for (int i = t; i < 4096; i += 256) {
            int r = i >> 6, c = i & 63;
            int k = k0 + r;
            if (k < 432) W_ih_T[(size_t)k * 1024 + j0 + c] = tile[c][r];
        }
    } else if (blk == 16) {
        const int aids[7] = {0, 1, 4, 2, 3, 5, 6};
        for (int s = 0; s < 7; s++) {
            int aid = aids[s];
            for (int j = t; j < 1024; j += 256) {
                float v = b_ih[j] + b_hh[j];
                #pragma unroll
                for (int k = 0; k < 16; k++)
                    v += addr_emb[aid * 16 + k] * W_ih[(size_t)j * 432 + 416 + k];
                bias_all[s * 1024 + j] = v;
            }
        }
    } else if (blk == 17) {
        for (int p = 0; p < 3; p++)
            for (int j = t; j < 1024; j += 256) {
                float v = 0.f;
                #pragma unroll
                for (int k = 0; k < 16; k++)
                    v += pid_emb[p * 16 + k] * W_ih[(size_t)j * 432 + 400 + k];
                pid_rows[p * 1024 + j] = v;
            }
        for (int p = 0; p < 2; p++)
            for (int j = t; j < 1024; j += 256) {
                float v = 0.f;
                #pragma unroll
                for (int k = 0; k < 16; k++)
                    v += sid_emb[p * 16 + k] * W_ih[(size_t)j * 432 + 400 + k];
                sid_rows[p * 1024 + j] = v;
            }
    } else if (blk == 18) {
        for (int i = t; i < 10000; i += 256) {
            int o = i / 100, k = i % 100;
            w2t[k * 100 + o] = mlp_w2[i];
        }
        for (int i = t; i < 1600; i += 256) {
            int o = i / 100, k = i % 100;
            w3t[k * 16 + o] = mlp_w3[i];
        }
    } else if (blk == 19) {
        for (int i = t; i < 384; i += 256) {
            int ic = i / 12, k = i % 12;
            float v = 0.f;
            if (k < 9) v = conv1_w[ic * 9 + k];
            else if (k == 9) v = conv1_b[ic];
            w1p[i] = v;
        }
        // Btg[(tap*16 + oc)*32 + ic] = conv2_w[(oc*32+ic)*9 + tap]
        for (int i = t; i < 4608; i += 256) {
            int tap = i >> 9;
            int rem = i & 511;
            int oc = rem >> 5, ic = rem & 31;
            Btg[i] = f2bf(conv2_w[(size_t)(oc * 32 + ic) * 9 + tap]);
        }
    } else if (blk < 28) {
        // W_hh (1024x256) fp32 -> bf16, same [n][k] layout
        int seg = blk - 20;  // 0..7
        for (int i = seg * 32768 + t; i < (seg + 1) * 32768; i += 256)
            Wb[i] = f2bf(W_hh[i]);
    } else {
        // W_obs rows of W_ih -> bf16 [col][448], k >= 400 zero
        int col0 = (blk - 28) * 64;  // 16 blocks x 64 cols
        for (int i = t; i < 64 * AK; i += 256) {
            int c = col0 + i / AK, k = i % AK;
            Wobs_b[(size_t)c * AK + k] = (k < 400) ? f2bf(W_ih[(size_t)c * 432 + k]) : (ushort_t)0;
        }
    }
}

// ---------------------------------------------------------------------------
// Conv encoder v7: v6 structure, spill-free.
//   __launch_bounds__(512, 2): occupancy is LDS-bound at 2 blocks/CU (= 4
//   waves/SIMD) regardless, so the 256-VGPR cap costs nothing and removes
//   the scratch spill that R4's 128-cap forced (173 MB/dispatch HBM writes).
//   Bv fragments loaded per conv2 phase (Btg L1-resident) instead of held
//   kernel-lifetime: -36 VGPRs across conv1.
// ---------------------------------------------------------------------------
#define CE_RS 640   // cE row stride in ushorts (16 pos * 40)
#define CO_RS 680   // cO row stride in ushorts (17 pos * 40)
#define SM2S 72     // sm2 row stride in floats (18 16B-units, XOR-swizzled)
__global__ __launch_bounds__(512, 2) void conv_kernel(
    const float* __restrict__ obs, const float* __restrict__ w1p,
    const ushort_t* __restrict__ Btg, const float* __restrict__ b2,
    ushort_t* __restrict__ obs_emb_b)
{
    __shared__ __align__(16) ushort_t cE[17 * CE_RS];  // 21760 B
    __shared__ __align__(16) ushort_t cO[17 * CO_RS];  // 23120 B
    __shared__ __align__(16) float c2s[16 * 260];      // 16640 B
    __shared__ __align__(16) float sm2[33 * SM2S];     // 9504 B
    __shared__ __align__(16) float w1s[384];           // 1536 B
    const int b = blockIdx.x, t = threadIdx.x;
    const float* og = obs + (size_t)b * 4096;

    const int w = t >> 6, L = t & 63, q = L >> 4, ln = L & 15;

    // zero: cE buffer row 0 (c1 row -1), cO row 0, cO pos0 (col -1) rows 1..16
    {
        uint_t* zE = (uint_t*)cE;
        uint_t* zO = (uint_t*)cO;
        for (int i = t; i < CE_RS / 2; i += 512) zE[i] = 0;
        for (int i = t; i < CO_RS / 2; i += 512) zO[i] = 0;
        if (t < 320) {
            int row = (t / 20) + 1, d = t % 20;
            zO[row * (CO_RS / 2) + d] = 0;
        }
    }
    if (t < 96) ((float4*)w1s)[t] = ((const float4*)w1p)[t];
    if (t < 33) {
        int sw = (t >> 1) & 1;
        sm2[t * SM2S + sw * 4 + 3] = 0.f;  // logical col 3 (img col -1) = 0
    }

    // stage obs rows 32ph-1 .. 32ph+31 -> sm2 rows 0..32 (img col j at 4+j,
    // 16B-unit swizzle: logical unit u stored at u^((row>>1)&1))
    auto stage_obs = [&](int ph) {
        for (int i = t; i < 33 * 16; i += 512) {
            int row = i >> 4, c4 = i & 15;
            int sw = (row >> 1) & 1;
            int orow = 32 * ph - 1 + row;
            float4 v = float4{0.f, 0.f, 0.f, 0.f};
            if (orow >= 0) v = ((const float4*)(og + (size_t)orow * 64))[c4];
            *(float4*)&sm2[row * SM2S + ((1 + c4) ^ sw) * 4] = v;
        }
    };

    // conv1 phase: thread (r = t>>5, g = (t>>2)&7, icq = t&3) computes
    // c1 row 16ph+r, cols 4g..4g+3, ics 8icq..8icq+7.
    auto conv1_phase = [&](int ph) {
        const int r = t >> 5, g = (t >> 2) & 7, icq = t & 3;
        const int brow = ph ? r : (r + 1);
        // Pt[d][j] = obs[2*(16ph+r)-1+d][8g-4+j]; logical sm2 cols 8g..8g+11
        // = units 2g..2g+2 (phys unit = logical ^ sw(row)).
        float Pt[3][12];
        #pragma unroll
        for (int d = 0; d < 3; d++) {
            int row = 2 * r + d;
            int sw = (row >> 1) & 1;
            const float* base = &sm2[row * SM2S];
            #pragma unroll
            for (int j4 = 0; j4 < 3; j4++) {
                float4 v = *(const float4*)(base + ((2 * g + j4) ^ sw) * 4);
                Pt[d][j4 * 4 + 0] = v.x; Pt[d][j4 * 4 + 1] = v.y;
                Pt[d][j4 * 4 + 2] = v.z; Pt[d][j4 * 4 + 3] = v.w;
            }
        }
        uint_t pk[4][4];  // [pos][4 dwords = 8 ic bf16]
        #pragma unroll
        for (int ih = 0; ih < 2; ih++) {
            float W[4][10];
            #pragma unroll
            for (int i = 0; i < 4; i++) {
                const float* qw = &w1s[(icq * 8 + ih * 4 + i) * 12];
                float4 qa = *(const float4*)qw;
                float4 qb = *(const float4*)(qw + 4);
                float2 qc = *(const float2*)(qw + 8);
                W[i][0] = qa.x; W[i][1] = qa.y; W[i][2] = qa.z; W[i][3] = qa.w;
                W[i][4] = qb.x; W[i][5] = qb.y; W[i][6] = qb.z; W[i][7] = qb.w;
                W[i][8] = qc.x; W[i][9] = qc.y;
            }
            #pragma unroll
            for (int p = 0; p < 4; p++) {
                float sv[4];
                #pragma unroll
                for (int i = 0; i < 4; i++) {
                    float s = W[i][9];
                    #pragma unroll
                    for (int d = 0; d < 3; d++)
                        #pragma unroll
                        for (int dx = 0; dx < 3; dx++)
                            s += W[i][d * 3 + dx] * Pt[d][2 * p + 3 + dx];
                    sv[i] = fmaxf(s, 0.f);
                }
                uint_t w0, w1;
                asm("v_cvt_pk_bf16_f32 %0, %1, %2" : "=v"(w0) : "v"(sv[0]), "v"(sv[1]));
                asm("v_cvt_pk_bf16_f32 %0, %1, %2" : "=v"(w1) : "v"(sv[2]), "v"(sv[3]));
                pk[p][ih * 2 + 0] = w0;
                pk[p][ih * 2 + 1] = w1;
            }
        }
        #pragma unroll
        for (int p = 0; p < 4; p++) {
            int c = 4 * g + p;
            ushort_t* dst = (c & 1)
                ? &cO[brow * CO_RS + ((c + 1) >> 1) * 40 + icq * 8]
                : &cE[brow * CE_RS + (c >> 1) * 40 + icq * 8];
            *(uint4*)dst = uint4{pk[p][0], pk[p][1], pk[p][2], pk[p][3]};
        }
    };

    // conv2 phase: wave w -> output row y = 8ph+w; 9 tap-MFMAs; epilogue to c2s
    auto conv2_phase = [&](int ph) {
        // B-fragments loaded per phase (Btg L1-resident) to keep conv1
        // register pressure low.
        bf16x8 Bv[9];
        #pragma unroll
        for (int tap = 0; tap < 9; tap++)
            Bv[tap] = *reinterpret_cast<const bf16x8*>(&Btg[(tap * 16 + ln) * 32 + q * 8]);
        const int y = 8 * ph + w;
        f32x4v C = {0.f, 0.f, 0.f, 0.f};
        #pragma unroll
        for (int dy = 0; dy < 3; dy++) {
            int br = 2 * y + dy;          // (c1row+1); c1row = 2y-1+dy
            if (br >= 17) br -= 17;
            bf16x8 a0 = *reinterpret_cast<const bf16x8*>(&cO[br * CO_RS + ln * 40 + q * 8]);        // dx=0: col 2m-1
            bf16x8 a1 = *reinterpret_cast<const bf16x8*>(&cE[br * CE_RS + ln * 40 + q * 8]);        // dx=1: col 2m
            bf16x8 a2 = *reinterpret_cast<const bf16x8*>(&cO[br * CO_RS + (ln + 1) * 40 + q * 8]);  // dx=2: col 2m+1
            C = __builtin_amdgcn_mfma_f32_16x16x32_bf16(a0, Bv[dy * 3 + 0], C, 0, 0, 0);
            C = __builtin_amdgcn_mfma_f32_16x16x32_bf16(a1, Bv[dy * 3 + 1], C, 0, 0, 0);
            C = __builtin_amdgcn_mfma_f32_16x16x32_bf16(a2, Bv[dy * 3 + 2], C, 0, 0, 0);
        }
        float bb2 = b2[ln];
        float4 o;
        o.x = fmaxf(C[0] + bb2, 0.f);
        o.y = fmaxf(C[1] + bb2, 0.f);
        o.z = fmaxf(C[2] + bb2, 0.f);
        o.w = fmaxf(C[3] + bb2, 0.f);
        *(float4*)&c2s[ln * 260 + y * 16 + q * 4] = o;  // oc=ln, x=q*4+r
    };

    stage_obs(0);
    __syncthreads();
    conv1_phase(0);            // writes buffer rows 1..16 (c1 rows 0..15)
    __syncthreads();
    stage_obs(1);              // global loads overlap phase-0 MFMAs
    conv2_phase(0);            // reads rows 0..16; c2 rows 0..7
    __syncthreads();
    conv1_phase(1);            // writes buffer rows 0..15 (c1 rows 16..31)
    __syncthreads();
    conv2_phase(1);            // c2 rows 8..15
    __syncthreads();

    // pool 3x3 stride 3 -> LDS restage -> vectorized bf16 store (448 padded)
    ushort_t* ew = (ushort_t*)w1s;   // 896 B needed; w1s dead after conv1
    if (t < 400) {
        int c = t / 25, rem = t % 25, py = rem / 5, px = rem % 5;
        float s = 0.f;
        #pragma unroll
        for (int dy = 0; dy < 3; dy++)
            #pragma unroll
            for (int dx = 0; dx < 3; dx++)
                s += c2s[c * 260 + (3 * py + dy) * 16 + 3 * px + dx];
        ew[t] = f2bf(s * (1.f / 9.f));
    } else if (t < AK) {
        ew[t] = 0;
    }
    __syncthreads();
    if (t < 56)
        ((uint4*)(obs_emb_b + (size_t)b * AK))[t] = ((const uint4*)ew)[t];
}

// ---------------------------------------------------------------------------
// obs_part (bf16) = obs_emb_b (B x 448 bf16) @ Wobs_b.T -> (B x 1024), MFMA.
// Store restaged through LDS -> full-line uint4 global writes.
// ---------------------------------------------------------------------------
__global__ __launch_bounds__(256) void obs_gemm(
    const ushort_t* __restrict__ Ab, const ushort_t* __restrict__ Wob,
    ushort_t* __restrict__ outp)
{
    __shared__ __align__(16) ushort_t As[64 * 72];   // 9216 B
    __shared__ __align__(16) ushort_t ob[64 * 132];  // 16896 B
    const int t = threadIdx.x;
    const int bm = blockIdx.x & 63, bu = blockIdx.x >> 6;
    const int b0 = bm * 64, n0 = bu * 128;
    const int w = t >> 6, L = t & 63, q = L >> 4, ln = L & 15;
    const int m0 = w * 16;

    f32x4v acc[8];
    #pragma unroll
    for (int i = 0; i < 8; i++) acc[i] = f32x4v{0.f, 0.f, 0.f, 0.f};

    for (int kc = 0; kc < 7; kc++) {
        // stage A chunk: 64 rows x 64 k (bf16)
        #pragma unroll
        for (int ii = 0; ii < 2; ii++) {
            int i = t + ii * 256;
            int row = i >> 3, c8 = i & 7;
            *(uint4*)&As[row * 72 + c8 * 8] =
                *(const uint4*)&Ab[(size_t)(b0 + row) * AK + kc * 64 + c8 * 8];
        }
        __syncthreads();
        bf16x8 a[2];
        #pragma unroll
        for (int ks = 0; ks < 2; ks++)
            a[ks] = *reinterpret_cast<const bf16x8*>(&As[(m0 + ln) * 72 + ks * 32 + q * 8]);
        #pragma unroll
        for (int ct = 0; ct < 8; ct++) {
            const ushort_t* wr = Wob + (size_t)(n0 + ct * 16 + ln) * AK + kc * 64 + q * 8;
            bf16x8 bv0 = *reinterpret_cast<const bf16x8*>(wr);
            bf16x8 bv1 = *reinterpret_cast<const bf16x8*>(wr + 32);
            acc[ct] = __builtin_amdgcn_mfma_f32_16x16x32_bf16(a[0], bv0, acc[ct], 0, 0, 0);
            acc[ct] = __builtin_amdgcn_mfma_f32_16x16x32_bf16(a[1], bv1, acc[ct], 0, 0, 0);
        }
        __syncthreads();
    }
    // restage C tile in LDS (bf16) then vectorized store
    #pragma unroll
    for (int ct = 0; ct < 8; ct++)
        #pragma unroll
        for (int j = 0; j < 4; j++)
            ob[(m0 + q * 4 + j) * 132 + ct * 16 + ln] = f2bf(acc[ct][j]);
    __syncthreads();
    #pragma unroll
    for (int p2 = 0; p2 < 4; p2++) {
        int idx = t + p2 * 256;
        int row = idx >> 4, c8 = idx & 15;
        uint4 v = *(const uint4*)&ob[row * 132 + c8 * 8];
        *(uint4*)&outp[(size_t)(b0 + row) * 1024 + n0 + c8 * 8] = v;
    }
}

// ---------------------------------------------------------------------------
// step0 elementwise: h=c=0 -> c0 (fp32), hb0 (bf16). pre = obs_part + bias0.
// ---------------------------------------------------------------------------
__global__ __launch_bounds__(256) void step0_ew(
    const ushort_t* __restrict__ obs_part, const float* __restrict__ bias_s,
    float* __restrict__ c_out, ushort_t* __restrict__ hb_out)
{
    const int R = blockIdx.x, u = threadIdx.x;
    float pre[4];
    #pragma unroll
    for (int g = 0; g < 4; g++)
        pre[g] = bf2f(obs_part[(size_t)R * 1024 + g * 256 + u]) + bias_s[g * 256 + u];
    float c2 = sigf(pre[0]) * tanh_fast(pre[2]);
    float hv = sigf(pre[3]) * tanh_fast(c2);
    c_out[(size_t)R * 256 + u] = c2;
    hb_out[(size_t)R * 256 + u] = f2bf(hv);
}

// ---------------------------------------------------------------------------
// MFMA LSTM step v2: short critical path.
//   - A-fragments loaded DIRECTLY from global (no hAs staging / barrier).
//   - obs_part slice (64x128 bf16) and c_in slice (64x32 f32) cooperatively
//     staged into conflict-free-padded LDS; latency hides under MFMAs.
//   - epilogue reads LDS, writes results back in-place (ps g0-slot / cs);
//     final phase stores full 64-256B segments (no 2B-store RMW).
//   DUAL=1: 1024 blocks, two independent steps in one launch.
// ---------------------------------------------------------------------------
template <int SAMP, int HEAD_N, int DUAL>
__global__ __launch_bounds__(512, 4) void lstm_mfma(
    const ushort_t* __restrict__ hb_in, const float* __restrict__ c_in,
    ushort_t* __restrict__ hb_out, float* __restrict__ c_out,
    const ushort_t* __restrict__ obs_part, const float* __restrict__ bias_s,
    const float* __restrict__ samp_rows, const int* __restrict__ samp_idx,
    const float* __restrict__ rp0_emb, const float* __restrict__ WsampT,
    const ushort_t* __restrict__ Wb,
    const float* __restrict__ head_w, const float* __restrict__ head_b,
    float* __restrict__ out, int out_off,
    const ushort_t* __restrict__ hb_in2, const float* __restrict__ c_in2,
    ushort_t* __restrict__ hb_out2, float* __restrict__ c_out2,
    const float* __restrict__ bias_s2, const int* __restrict__ samp_idx2,
    const float* __restrict__ head_w2, int out_off2)
{
    constexpr int PS_B = 64 * 132 * 2;   // 16896
    constexpr int CS_B = 64 * 36 * 4;    // 9216
    constexpr int EX_B = (SAMP == 2) ? (16 * 132 * 4 + 64 * 20 * 4)   // wsmp + re
                                     : (3 * 256 * 4 + 64 * 8 * 3 * 4); // hws + red
    __shared__ __align__(16) char smem[PS_B + CS_B + EX_B];
    ushort_t* ps = (ushort_t*)smem;               // [64][132] bf16
    float* cs = (float*)(smem + PS_B);            // [64][36] f32
    float* hws = (float*)(smem + PS_B + CS_B);    // head weights
    float* red = (float*)(smem + PS_B + CS_B + 3 * 256 * 4);
    float* wsmp = (float*)(smem + PS_B + CS_B);   // [16][132] f32 (SAMP2)
    float* re = (float*)(smem + PS_B + CS_B + 16 * 132 * 4);  // [64][20]

    const int t = threadIdx.x;
    const int half  = DUAL ? (int)(blockIdx.x >> 9) : 0;
    const int inner = DUAL ? (int)(blockIdx.x & 511) : (int)blockIdx.x;
    const int bm = inner & 63, bu = inner >> 6;
    const int b0 = bm * 64;

    const ushort_t* hbi = (DUAL && half) ? hb_in2 : hb_in;
    const float* cip    = (DUAL && half) ? c_in2 : c_in;
    ushort_t* hbo       = (DUAL && half) ? hb_out2 : hb_out;
    float* cop          = (DUAL && half) ? c_out2 : c_out;
    const float* biasp  = (DUAL && half) ? bias_s2 : bias_s;
    const int* sidx     = (DUAL && half) ? samp_idx2 : samp_idx;
    const float* hwp    = (DUAL && half) ? head_w2 : head_w;
    const int ooff      = (DUAL && half) ? out_off2 : out_off;
    const bool do_head  = (HEAD_N > 0) && (bu == 0) && (hwp != nullptr);

    const int w = t >> 6, L = t & 63, q = L >> 4, ln = L & 15;
    const int m0 = (w & 3) * 16, wg = w >> 2;
    const int U0 = bu * 32;
    const int unit = U0 + wg * 16 + ln;

    // A fragments: direct global loads (hb L2-resident)
    bf16x8 a[8];
    {
        const ushort_t* arow = hbi + (size_t)(b0 + m0 + ln) * 256 + q * 8;
        #pragma unroll
        for (int kk = 0; kk < 8; kk++)
            a[kk] = *reinterpret_cast<const bf16x8*>(arow + kk * 32);
    }

    // cooperative staging (hidden under MFMAs)
    #pragma unroll
    for (int p = 0; p < 2; p++) {
        int idx = t + p * 512;
        int row = idx >> 4, c8 = idx & 15;
        int g = c8 >> 2, cc = (c8 & 3) * 8;
        uint4 v = *(const uint4*)&obs_part[(size_t)(b0 + row) * 1024 + g * 256 + U0 + cc];
        *(uint4*)&ps[row * 132 + c8 * 8] = v;
    }
    {
        int row = t >> 3, c4 = t & 7;
        float4 v = *(const float4*)&cip[(size_t)(b0 + row) * 256 + U0 + c4 * 4];
        *(float4*)&cs[row * 36 + c4 * 4] = v;
    }
    if (SAMP == 2) {
        int k = t >> 5, c4 = t & 31;
        float4 v = *(const float4*)&WsampT[(size_t)k * 1024 + ((c4 * 4) >> 5) * 256 + U0 + ((c4 * 4) & 31)];
        *(float4*)&wsmp[k * 132 + c4 * 4] = v;
        if (t < 256) {
            int row = t >> 2, d4 = t & 3;
            float4 e = *(const float4*)&rp0_emb[(size_t)(b0 + row) * 16 + d4 * 4];
            *(float4*)&re[row * 20 + d4 * 4] = e;
        }
    }
    if (do_head)
        for (int i = t; i < HEAD_N * 256; i += 512) hws[i] = hwp[i];

    // MFMA: 4 gates x 8 K-chunks
    f32x4v acc[4];
    #pragma unroll
    for (int g = 0; g < 4; g++) {
        f32x4v z = {0.f, 0.f, 0.f, 0.f};
        const ushort_t* wrow = Wb + (size_t)(g * 256 + unit) * 256 + q * 8;
        #pragma unroll
        for (int kk = 0; kk < 8; kk++) {
            bf16x8 bv = *reinterpret_cast<const bf16x8*>(wrow + kk * 32);
            z = __builtin_amdgcn_mfma_f32_16x16x32_bf16(a[kk], bv, z, 0, 0, 0);
        }
        acc[g] = z;
    }
    __syncthreads();   // staged data visible

    float bsv[4];
    #pragma unroll
    for (int g = 0; g < 4; g++) bsv[g] = biasp[g * 256 + unit];

    const int cc = wg * 16 + ln;
    #pragma unroll
    for (int r = 0; r < 4; r++) {
        const int row = m0 + q * 4 + r;
        const int R = b0 + row;
        float pre[4];
        #pragma unroll
        for (int g = 0; g < 4; g++)
            pre[g] = acc[g][r] + bf2f(ps[row * 132 + g * 32 + cc]) + bsv[g];
        if (SAMP == 1) {
            int si = sidx[R];
            #pragma unroll
            for (int g = 0; g < 4; g++) pre[g] += samp_rows[si * 1024 + g * 256 + unit];
        }
        if (SAMP == 2) {
            #pragma unroll
            for (int k = 0; k < 16; k++) {
                float e = re[row * 20 + k];
                #pragma unroll
                for (int g = 0; g < 4; g++) pre[g] += e * wsmp[k * 132 + g * 32 + cc];
            }
        }
        float ci = cs[row * 36 + cc];
        float c2 = sigf(pre[1]) * ci + sigf(pre[0]) * tanh_fast(pre[2]);
        float hv = sigf(pre[3]) * tanh_fast(c2);
        cs[row * 36 + cc] = c2;              // in-place (own cell)
        ps[row * 132 + cc] = f2bf(hv);       // g0 slot (own cell, already read)
    }
    __syncthreads();

    // vectorized stores
    {
        int row = t >> 3, c4 = t & 7;
        float4 v = *(const float4*)&cs[row * 36 + c4 * 4];
        *(float4*)&cop[(size_t)(b0 + row) * 256 + U0 + c4 * 4] = v;
    }
    if (t < 256) {
        int row = t >> 2, c8 = t & 3;
        uint4 v = *(const uint4*)&ps[row * 132 + c8 * 8];
        *(uint4*)&hbo[(size_t)(b0 + row) * 256 + U0 + c8 * 8] = v;
    }

    if (do_head) {
        const int row = t >> 3, seg = t & 7;
        const ushort_t* hrow = hbi + (size_t)(b0 + row) * 256 + seg * 32;
        float part[3] = {0.f, 0.f, 0.f};
        #pragma unroll
        for (int j = 0; j < 4; j++) {
            uint4 v = *(const uint4*)(hrow + j * 8);
            uint_t dw[4] = {v.x, v.y, v.z, v.w};
            #pragma unroll
            for (int d = 0; d < 4; d++) {
                float f0 = __uint_as_float(dw[d] << 16);
                float f1 = __uint_as_float(dw[d] & 0xffff0000u);
                int k = seg * 32 + j * 8 + d * 2;
                #pragma unroll
                for (int n = 0; n < HEAD_N; n++)
                    part[n] += f0 * hws[n * 256 + k] + f1 * hws[n * 256 + k + 1];
            }
        }
        #pragma unroll
        for (int n = 0; n < HEAD_N; n++) red[(row * 8 + seg) * 3 + n] = part[n];
        __syncthreads();
        if (t < 64) {
            #pragma unroll
            for (int n = 0; n < HEAD_N; n++) {
                float s = head_b[n];
                #pragma unroll
                for (int p = 0; p < 8; p++) s += red[(t * 8 + p) * 3 + n];
                out[(size_t)(b0 + t) * OUT_W + ooff + n] = s;
            }
        }
    }
}

// ---------------------------------------------------------------------------
// rp head: out[:, off:off+2] = rp[:, :2] + exp(rp[:, 2:]) * eps, from hb.
// ---------------------------------------------------------------------------
__global__ __launch_bounds__(256) void rp_head(
    const ushort_t* __restrict__ hb, const float* __restrict__ head_w,
    const float* __restrict__ head_b, const float* __restrict__ eps,
    float* __restrict__ out, int out_off, float* __restrict__ rp_store)
{
    __shared__ float hw[1024];
    __shared__ float red[64 * 4 * 4];
    const int t = threadIdx.x;
    const int b0 = blockIdx.x * 64;
    for (int i = t; i < 1024; i += 256) hw[i] = head_w[i];
    __syncthreads();
    const int r = t >> 2, p = t & 3;
    {
        const int R = b0 + r;
        float part[4] = {0.f, 0.f, 0.f, 0.f};
        const ushort_t* hr = hb + (size_t)R * 256 + p * 64;
        #pragma unroll
        for (int j = 0; j < 8; j++) {
            uint4 v = *reinterpret_cast<const uint4*>(hr + j * 8);
            uint_t dw[4] = {v.x, v.y, v.z, v.w};
            #pragma unroll
            for (int d = 0; d < 4; d++) {
                float f0 = __uint_as_float(dw[d] << 16);
                float f1 = __uint_as_float(dw[d] & 0xffff0000u);
                int k = p * 64 + j * 8 + d * 2;
                #pragma unroll
                for (int n = 0; n < 4; n++)
                    part[n] += f0 * hw[n * 256 + k] + f1 * hw[n * 256 + k + 1];
            }
        }
        #pragma unroll
        for (int n = 0; n < 4; n++) red[(r * 4 + p) * 4 + n] = part[n];
    }
    __syncthreads();
    if (t < 64) {
        const int R = b0 + t;
        float s[4];
        #pragma unroll
        for (int n = 0; n < 4; n++) {
            float v = head_b[n];
            #pragma unroll
            for (int p2 = 0; p2 < 4; p2++) v += red[(t * 4 + p2) * 4 + n];
            s[n] = v;
        }
        float v0 = s[0] + __expf(s[2]) * eps[(size_t)R * 2 + 0];
        float v1 = s[1] + __expf(s[3]) * eps[(size_t)R * 2 + 1];
        out[(size_t)R * OUT_W + out_off + 0] = v0;
        out[(size_t)R * OUT_W + out_off + 1] = v1;
        if (rp_store) {
            rp_store[(size_t)R * 2 + 0] = v0;
            rp_store[(size_t)R * 2 + 1] = v1;
        }
    }
}

// ---------------------------------------------------------------------------
// MLP: rp0 (B x 2) -> 100 -> 100 -> rp0_emb (B x 16)
// ---------------------------------------------------------------------------
__global__ __launch_bounds__(128) void mlp_kernel(
    const float* __restrict__ rp0, const float* __restrict__ w1,
    const float* __restrict__ b1, const float* __restrict__ w2t,
    const float* __restrict__ b2, const float* __restrict__ w3t,
    const float* __restrict__ b3, float* __restrict__ emb)
{
    __shared__ float z1[100], z2[100];
    int row = blockIdx.x, t = threadIdx.x;
    float r0 = rp0[(size_t)row * 2], r1 = rp0[(size_t)row * 2 + 1];
    if (t < 100) z1[t] = tanh_fast(b1[t] + w1[t * 2] * r0 + w1[t * 2 + 1] * r1);
    __syncthreads();
    if (t < 100) {
        float s = b2[t];
        for (int k = 0; k < 100; k++) s += w2t[k * 100 + t] * z1[k];
        z2[t] = tanh_fast(s);
    }
    __syncthreads();
    if (t < 16) {
        float s = b3[t];
        for (int k = 0; k < 100; k++) s += w3t[k * 16 + t] * z2[k];
        emb[(size_t)row * 16 + t] = s;
    }
}

// ---------------------------------------------------------------------------
extern "C" void kernel_launch(void* const* d_in, const int* in_sizes, int n_in,
                              void* d_out, int out_size, void* d_ws, size_t ws_size,
                              hipStream_t stream)
{
    const float* obs        = (const float*)d_in[0];
    const int*   program_id = (const int*)d_in[1];
    const int*   shape_id   = (const int*)d_in[2];
    const int*   shape_id_0 = (const int*)d_in[3];
    const int*   shape_id_1 = (const int*)d_in[4];
    const float* eps_rp     = (const float*)d_in[5];
    const float* eps_rp0    = (const float*)d_in[6];
    const float* eps_rp1    = (const float*)d_in[7];
    const float* conv1_w    = (const float*)d_in[8];
    const float* conv1_b    = (const float*)d_in[9];
    const float* conv2_w    = (const float*)d_in[10];
    const float* conv2_b    = (const float*)d_in[11];
    const float* mlp_w1     = (const float*)d_in[12];
    const float* mlp_b1     = (const float*)d_in[13];
    const float* mlp_w2     = (const float*)d_in[14];
    const float* mlp_b2     = (const float*)d_in[15];
    const float* mlp_w3     = (const float*)d_in[16];
    const float* mlp_b3     = (const float*)d_in[17];
    const float* W_ih       = (const float*)d_in[18];
    const float* b_ih       = (const float*)d_in[19];
    const float* W_hh       = (const float*)d_in[20];
    const float* b_hh       = (const float*)d_in[21];
    const float* addr_emb   = (const float*)d_in[22];
    const float* pid_emb    = (const float*)d_in[23];
    const float* sid_emb    = (const float*)d_in[24];
    const float* pid_ext_w  = (const float*)d_in[25];
    const float* pid_ext_b  = (const float*)d_in[26];
    const float* sid_ext_w  = (const float*)d_in[27];
    const float* sid_ext_b  = (const float*)d_in[28];
    const float* rp_ext_w   = (const float*)d_in[29];
    const float* rp_ext_b   = (const float*)d_in[30];
    float* out = (float*)d_out;

    // workspace layout (float slots, 16B-aligned chunks)
    float* ws = (float*)d_ws;
    size_t off = 0;
    float* W_ih_T   = ws + off; off += 432 * 1024;              // fp32
    ushort_t* Wb    = (ushort_t*)(ws + off); off += 131072;     // bf16 1024x256
    float* bias_all = ws + off; off += 7 * 1024;
    float* pid_rows = ws + off; off += 3 * 1024;
    float* sid_rows = ws + off; off += 2 * 1024;
    ushort_t* obs_emb_b = (ushort_t*)(ws + off); off += (size_t)BATCH * AK / 2;  // bf16 Bx448
    ushort_t* Wobs_b    = (ushort_t*)(ws + off); off += (size_t)1024 * AK / 2;   // bf16 1024x448
    ushort_t* obs_part = (ushort_t*)(ws + off); off += (size_t)BATCH * 512;  // bf16 Bx1024
    ushort_t* hb0 = (ushort_t*)(ws + off); off += (size_t)BATCH * 128;      // bf16 Bx256
    ushort_t* hbA = (ushort_t*)(ws + off); off += (size_t)BATCH * 128;
    ushort_t* hbB = (ushort_t*)(ws + off); off += (size_t)BATCH * 128;
    ushort_t* hbC = (ushort_t*)(ws + off); off += (size_t)BATCH * 128;
    ushort_t* hbA2 = (ushort_t*)(ws + off); off += (size_t)BATCH * 128;
    ushort_t* hbB2 = (ushort_t*)(ws + off); off += (size_t)BATCH * 128;
    float* c0 = ws + off; off += (size_t)BATCH * 256;
    float* cA = ws + off; off += (size_t)BATCH * 256;
    float* cB = ws + off; off += (size_t)BATCH * 256;
    float* cC = ws + off; off += (size_t)BATCH * 256;
    float* cD = ws + off; off += (size_t)BATCH * 256;   // dump for terminal c
    float* cA2 = ws + off; off += (size_t)BATCH * 256;
    float* rp0      = ws + off; off += (size_t)BATCH * 2;
    float* rp0_emb  = ws + off; off += (size_t)BATCH * 16;
    float* w2t = ws + off; off += 10000;
    float* w3t = ws + off; off += 1600;
    float* w1p = ws + off; off += 384;
    ushort_t* Btg = (ushort_t*)(ws + off); off += 2304;  // 4608 bf16
    float* WsampT = W_ih_T + (size_t)400 * 1024;  // rows 400..415 of W_ih_T (fp32)

    prep_kernel<<<44, 256, 0, stream>>>(W_ih, W_hh, b_ih, b_hh, addr_emb,
                                        pid_emb, sid_emb, mlp_w2, mlp_w3,
                                        conv1_w, conv1_b, conv2_w,
                                        W_ih_T, Wb, bias_all, pid_rows,
                                        sid_rows, w2t, w3t, w1p, Btg, Wobs_b);
    conv_kernel<<<BATCH, 512, 0, stream>>>(obs, w1p, Btg, conv2_b, obs_emb_b);
    obs_gemm<<<512, 256, 0, stream>>>(obs_emb_b, Wobs_b, obs_part);

    // step0 (aid 0): h=c=0 -> hb0, c0 (pid head on h0 folded into step1)
    step0_ew<<<BATCH, 256, 0, stream>>>(obs_part, bias_all + 0 * 1024, c0, hb0);

    // merged step1 (aid 1, head pid on h0 -> cols 0..2) + step1b (aid 2, no head)
    lstm_mfma<1, 3, 1><<<1024, 512, 0, stream>>>(
        hb0, c0, hbA, cA, obs_part, bias_all + 1 * 1024,
        pid_rows, program_id, nullptr, nullptr, Wb,
        pid_ext_w, pid_ext_b, out, 0,
        hb0, c0, hbA2, cA2, bias_all + 3 * 1024, program_id, nullptr, 0);
    // merged step2 (aid 4, head sid on h1 -> cols 3..4) + step2b (aid 3, head sid0 on h1b -> cols 7..8)
    lstm_mfma<1, 2, 1><<<1024, 512, 0, stream>>>(
        hbA, cA, hbB, cD, obs_part, bias_all + 2 * 1024,
        sid_rows, shape_id, nullptr, nullptr, Wb,
        sid_ext_w, sid_ext_b, out, 3,
        hbA2, cA2, hbB2, cB, bias_all + 4 * 1024, shape_id_0, sid_ext_w, 7);
    // rp_b0 head on h2 (hbB) -> cols 5..6
    rp_head<<<64, 256, 0, stream>>>(hbB, rp_ext_w, rp_ext_b, eps_rp, out, 5, nullptr);
    // step3b (aid 5): hbB2,cB -> hbC,cC; samp sid[shape_id_1]; head = sid1(2) on h2b -> cols 9..10
    lstm_mfma<1, 2, 0><<<512, 512, 0, stream>>>(
        hbB2, cB, hbC, cC, obs_part, bias_all + 5 * 1024,
        sid_rows, shape_id_1, nullptr, nullptr, Wb,
        sid_ext_w, sid_ext_b, out, 9,
        nullptr, nullptr, nullptr, nullptr, nullptr, nullptr, nullptr, 0);
    // rp0 head on h3b (hbC) -> cols 11..12, store rp0
    rp_head<<<64, 256, 0, stream>>>(hbC, rp_ext_w, rp_ext_b, eps_rp0, out, 11, rp0);
    mlp_kernel<<<BATCH, 128, 0, stream>>>(rp0, mlp_w1, mlp_b1, w2t, mlp_b2,
                                          w3t, mlp_b3, rp0_emb);
    // step4b (aid 6): hbC,cC -> hbB,cD; samp = rp0_emb @ WsampT; no head
    lstm_mfma<2, 0, 0><<<512, 512, 0, stream>>>(
        hbC, cC, hbB, cD, obs_part, bias_all + 6 * 1024,
        nullptr, nullptr, rp0_emb, WsampT, Wb,
        nullptr, nullptr, out, 0,
        nullptr, nullptr, nullptr, nullptr, nullptr, nullptr, nullptr, 0);
    // rp1 head on h4b (hbB) -> cols 13..14
    rp_head<<<64, 256, 0, stream>>>(hbB, rp_ext_w, rp_ext_b, eps_rp1, out, 13, nullptr);
}

// Round 6
// 424.768 us; speedup vs baseline: 1.2182x; 1.0958x over previous
//
#include <hip/hip_runtime.h>
#include <hip/hip_bf16.h>
#include <math.h>

#define BATCH 4096
#define HID 256
#define OUT_W 15
#define AK 448   // padded K for obs GEMM (400 valid + 48 zeros)

typedef unsigned short ushort_t;
typedef unsigned int uint_t;

using bf16x8 = __attribute__((ext_vector_type(8))) short;
using f32x4v = __attribute__((ext_vector_type(4))) float;
using f32x2 = __attribute__((ext_vector_type(2))) float;

__device__ __forceinline__ float sigf(float x) { return 1.0f / (1.0f + __expf(-x)); }
__device__ __forceinline__ float tanh_fast(float x) { return 1.0f - 2.0f / (__expf(2.0f * x) + 1.0f); }
__device__ __forceinline__ float bf2f(ushort_t u) { return __uint_as_float(((uint_t)u) << 16); }
__device__ __forceinline__ ushort_t f2bf(float x) {
    uint_t b = __float_as_uint(x);
    return (ushort_t)((b + 0x7fffu + ((b >> 16) & 1u)) >> 16);
}

// ---------------------------------------------------------------------------
// Prep (68 blocks): WsampT tile, biases, samp tables, mlp transposes,
// conv packs (w1pp pair-interleaved for v_pk_fma_f32), conv2 B-frags,
// W_hh -> bf16 (16 blocks), W_obs -> bf16 (32 blocks).
// ---------------------------------------------------------------------------
__global__ __launch_bounds__(256) void prep_kernel(
    const float* __restrict__ W_ih, const float* __restrict__ W_hh,
    const float* __restrict__ b_ih, const float* __restrict__ b_hh,
    const float* __restrict__ addr_emb, const float* __restrict__ pid_emb,
    const float* __restrict__ sid_emb,
    const float* __restrict__ mlp_w2, const float* __restrict__ mlp_w3,
    const float* __restrict__ conv1_w, const float* __restrict__ conv1_b,
    const float* __restrict__ conv2_w,
    float* __restrict__ W_ih_T, ushort_t* __restrict__ Wb,
    float* __restrict__ bias_all, float* __restrict__ pid_rows,
    float* __restrict__ sid_rows, float* __restrict__ w2t, float* __restrict__ w3t,
    float* __restrict__ w1pp, ushort_t* __restrict__ Btg,
    ushort_t* __restrict__ Wobs_b)
{
    int blk = blockIdx.x, t = threadIdx.x;
    if (blk < 16) {
        // W_ih tile (64 cols j0, k 384..447) -> W_ih_T (WsampT source)
        __shared__ float tile[64][65];
        int j0 = blk * 64;
        int k0 = 384;
        for (int i = t; i < 4096; i += 256) {
            int r = i >> 6, c = i & 63;
            int k = k0 + c;
            tile[r][c] = (k < 432) ? W_ih[(size_t)(j0 + r) * 432 + k] : 0.f;
        }
        __syncthreads();
        for (int i = t; i < 4096; i += 256) {
            int r = i >> 6, c = i & 63;
            int k = k0 + r;
            if (k < 432) W_ih_T[(size_t)k * 1024 + j0 + c] = tile[c][r];
        }
    } else if (blk == 16) {
        const int aids[7] = {0, 1, 4, 2, 3, 5, 6};
        for (int s = 0; s < 7; s++) {
            int aid = aids[s];
            for (int j = t; j < 1024; j += 256) {
                float v = b_ih[j] + b_hh[j];
                #pragma unroll
                for (int k = 0; k < 16; k++)
                    v += addr_emb[aid * 16 + k] * W_ih[(size_t)j * 432 + 416 + k];
                bias_all[s * 1024 + j] = v;
            }
        }
    } else if (blk == 17) {
        for (int p = 0; p < 3; p++)
            for (int j = t; j < 1024; j += 256) {
                float v = 0.f;
                #pragma unroll
                for (int k = 0; k < 16; k++)
                    v += pid_emb[p * 16 + k] * W_ih[(size_t)j * 432 + 400 + k];
                pid_rows[p * 1024 + j] = v;
            }
        for (int p = 0; p < 2; p++)
            for (int j = t; j < 1024; j += 256) {
                float v = 0.f;
                #pragma unroll
                for (int k = 0; k < 16; k++)
                    v += sid_emb[p * 16 + k] * W_ih[(size_t)j * 432 + 400 + k];
                sid_rows[p * 1024 + j] = v;
            }
    } else if (blk == 18) {
        for (int i = t; i < 10000; i += 256) {
            int o = i / 100, k = i % 100;
            w2t[k * 100 + o] = mlp_w2[i];
        }
        for (int i = t; i < 1600; i += 256) {
            int o = i / 100, k = i % 100;
            w3t[k * 16 + o] = mlp_w3[i];
        }
    } else if (blk == 19) {
        // w1pp[icq][i][k][2]: pair halves = ics (icq*8+i, icq*8+4+i); k 0..8
        // taps, k=9 bias.  320 floats.
        for (int i = t; i < 320; i += 256) {
            int half = i & 1, idx = i >> 1;
            int k = idx % 10, pr = idx / 10;   // pr = icq*4 + i2
            int icq = pr >> 2, i2 = pr & 3;
            int ic = icq * 8 + i2 + half * 4;
            w1pp[i] = (k < 9) ? conv1_w[ic * 9 + k] : conv1_b[ic];
        }
        // Btg[(tap*16 + oc)*32 + ic] = conv2_w[(oc*32+ic)*9 + tap]
        for (int i = t; i < 4608; i += 256) {
            int tap = i >> 9;
            int rem = i & 511;
            int oc = rem >> 5, ic = rem & 31;
            Btg[i] = f2bf(conv2_w[(size_t)(oc * 32 + ic) * 9 + tap]);
        }
    } else if (blk < 36) {
        // W_hh (1024x256) fp32 -> bf16, same [n][k] layout (16 blocks)
        int seg = blk - 20;  // 0..15
        for (int i = seg * 16384 + t; i < (seg + 1) * 16384; i += 256)
            Wb[i] = f2bf(W_hh[i]);
    } else {
        // W_obs rows of W_ih -> bf16 [col][448], k >= 400 zero (32 blocks)
        int col0 = (blk - 36) * 32;
        for (int i = t; i < 32 * AK; i += 256) {
            int c = col0 + i / AK, k = i % AK;
            Wobs_b[(size_t)c * AK + k] = (k < 400) ? f2bf(W_ih[(size_t)c * 432 + k]) : (ushort_t)0;
        }
    }
}

// ---------------------------------------------------------------------------
// Conv encoder v8: v7 structure + packed-fp32 conv1 + pool-conflict-free c2s.
//   conv1 inner loop: f32x2 elementwise_fma (v_pk_fma_f32) over ic-pairs
//   (ic, ic+4) from the pair-interleaved w1pp table; broadcast-pair P built
//   per position.  ~22% fewer VALU issues; peak ~100 VGPR -> (512,4) safe.
//   c2s strides: per-oc 324, per-row 20 floats -> pool reads spread over
//   5 bank groups instead of 2 (the 16.3M-conflict source).
// ---------------------------------------------------------------------------
#define CE_RS 640   // cE row stride in ushorts (16 pos * 40)
#define CO_RS 680   // cO row stride in ushorts (17 pos * 40)
#define SM2S 72     // sm2 row stride in floats (18 16B-units, XOR-swizzled)
#define C2S_CS 324  // c2s per-oc stride (floats)
#define C2S_RS 20   // c2s per-row stride (floats)
__global__ __launch_bounds__(512, 4) void conv_kernel(
    const float* __restrict__ obs, const float* __restrict__ w1pp,
    const ushort_t* __restrict__ Btg, const float* __restrict__ b2,
    ushort_t* __restrict__ obs_emb_b)
{
    __shared__ __align__(16) ushort_t cE[17 * CE_RS];   // 21760 B
    __shared__ __align__(16) ushort_t cO[17 * CO_RS];   // 23120 B
    __shared__ __align__(16) float c2s[16 * C2S_CS];    // 20736 B
    __shared__ __align__(16) float sm2[33 * SM2S];      // 9504 B
    __shared__ __align__(16) float w1s[320];            // 1280 B
    const int b = blockIdx.x, t = threadIdx.x;
    const float* og = obs + (size_t)b * 4096;

    const int w = t >> 6, L = t & 63, q = L >> 4, ln = L & 15;

    // zero: cE buffer row 0 (c1 row -1), cO row 0, cO pos0 (col -1) rows 1..16
    {
        uint_t* zE = (uint_t*)cE;
        uint_t* zO = (uint_t*)cO;
        for (int i = t; i < CE_RS / 2; i += 512) zE[i] = 0;
        for (int i = t; i < CO_RS / 2; i += 512) zO[i] = 0;
        if (t < 320) {
            int row = (t / 20) + 1, d = t % 20;
            zO[row * (CO_RS / 2) + d] = 0;
        }
    }
    if (t < 80) ((float4*)w1s)[t] = ((const float4*)w1pp)[t];
    if (t < 33) {
        int sw = (t >> 1) & 1;
        sm2[t * SM2S + sw * 4 + 3] = 0.f;  // logical col 3 (img col -1) = 0
    }

    // stage obs rows 32ph-1 .. 32ph+31 -> sm2 rows 0..32 (img col j at 4+j,
    // 16B-unit swizzle: logical unit u stored at u^((row>>1)&1))
    auto stage_obs = [&](int ph) {
        for (int i = t; i < 33 * 16; i += 512) {
            int row = i >> 4, c4 = i & 15;
            int sw = (row >> 1) & 1;
            int orow = 32 * ph - 1 + row;
            float4 v = float4{0.f, 0.f, 0.f, 0.f};
            if (orow >= 0) v = ((const float4*)(og + (size_t)orow * 64))[c4];
            *(float4*)&sm2[row * SM2S + ((1 + c4) ^ sw) * 4] = v;
        }
    };

    // conv1 phase: thread (r = t>>5, g = (t>>2)&7, icq = t&3) computes
    // c1 row 16ph+r, cols 4g..4g+3, ics 8icq..8icq+7 via packed-fp32 pairs.
    auto conv1_phase = [&](int ph) {
        const int r = t >> 5, g = (t >> 2) & 7, icq = t & 3;
        const int brow = ph ? r : (r + 1);
        // Pt[d][j] = obs[2*(16ph+r)-1+d][8g-4+j]
        float Pt[3][12];
        #pragma unroll
        for (int d = 0; d < 3; d++) {
            int row = 2 * r + d;
            int sw = (row >> 1) & 1;
            const float* base = &sm2[row * SM2S];
            #pragma unroll
            for (int j4 = 0; j4 < 3; j4++) {
                float4 v = *(const float4*)(base + ((2 * g + j4) ^ sw) * 4);
                Pt[d][j4 * 4 + 0] = v.x; Pt[d][j4 * 4 + 1] = v.y;
                Pt[d][j4 * 4 + 2] = v.z; Pt[d][j4 * 4 + 3] = v.w;
            }
        }
        const float* wpbase = &w1s[icq * 80];   // [i][10 k][2]
        #pragma unroll
        for (int p = 0; p < 4; p++) {
            // broadcast pairs for this position (taps 0..8)
            f32x2 pbc[9];
            #pragma unroll
            for (int d = 0; d < 3; d++)
                #pragma unroll
                for (int dx = 0; dx < 3; dx++) {
                    float v = Pt[d][2 * p + 3 + dx];
                    pbc[d * 3 + dx] = f32x2{v, v};
                }
            f32x2 sall[4];   // [i]: {s_ic(icq*8+i), s_ic(icq*8+4+i)}
            #pragma unroll
            for (int i = 0; i < 4; i++) {
                const float* wp = wpbase + i * 20;
                float4 wv0 = *(const float4*)(wp);
                float4 wv1 = *(const float4*)(wp + 4);
                float4 wv2 = *(const float4*)(wp + 8);
                float4 wv3 = *(const float4*)(wp + 12);
                float4 wv4 = *(const float4*)(wp + 16);
                f32x2 W2[10] = {f32x2{wv0.x, wv0.y}, f32x2{wv0.z, wv0.w},
                                f32x2{wv1.x, wv1.y}, f32x2{wv1.z, wv1.w},
                                f32x2{wv2.x, wv2.y}, f32x2{wv2.z, wv2.w},
                                f32x2{wv3.x, wv3.y}, f32x2{wv3.z, wv3.w},
                                f32x2{wv4.x, wv4.y}, f32x2{wv4.z, wv4.w}};
                f32x2 a2 = W2[9];   // bias pair
                #pragma unroll
                for (int k = 0; k < 9; k++)
                    a2 = __builtin_elementwise_fma(pbc[k], W2[k], a2);
                a2 = __builtin_elementwise_max(a2, f32x2{0.f, 0.f});
                sall[i] = a2;
            }
            // pack ics (0..7)+icq*8: dwords (0,1)(2,3)(4,5)(6,7)
            uint_t d0, d1, d2, d3;
            asm("v_cvt_pk_bf16_f32 %0, %1, %2" : "=v"(d0) : "v"(sall[0].x), "v"(sall[1].x));
            asm("v_cvt_pk_bf16_f32 %0, %1, %2" : "=v"(d1) : "v"(sall[2].x), "v"(sall[3].x));
            asm("v_cvt_pk_bf16_f32 %0, %1, %2" : "=v"(d2) : "v"(sall[0].y), "v"(sall[1].y));
            asm("v_cvt_pk_bf16_f32 %0, %1, %2" : "=v"(d3) : "v"(sall[2].y), "v"(sall[3].y));
            int c = 4 * g + p;
            ushort_t* dst = (c & 1)
                ? &cO[brow * CO_RS + ((c + 1) >> 1) * 40 + icq * 8]
                : &cE[brow * CE_RS + (c >> 1) * 40 + icq * 8];
            *(uint4*)dst = uint4{d0, d1, d2, d3};
        }
    };

    // conv2 phase: wave w -> output row y = 8ph+w; 9 tap-MFMAs; epilogue to c2s
    auto conv2_phase = [&](int ph) {
        bf16x8 Bv[9];
        #pragma unroll
        for (int tap = 0; tap < 9; tap++)
            Bv[tap] = *reinterpret_cast<const bf16x8*>(&Btg[(tap * 16 + ln) * 32 + q * 8]);
        const int y = 8 * ph + w;
        f32x4v C = {0.f, 0.f, 0.f, 0.f};
        #pragma unroll
        for (int dy = 0; dy < 3; dy++) {
            int br = 2 * y + dy;          // (c1row+1); c1row = 2y-1+dy
            if (br >= 17) br -= 17;
            bf16x8 a0 = *reinterpret_cast<const bf16x8*>(&cO[br * CO_RS + ln * 40 + q * 8]);        // dx=0
            bf16x8 a1 = *reinterpret_cast<const bf16x8*>(&cE[br * CE_RS + ln * 40 + q * 8]);        // dx=1
            bf16x8 a2 = *reinterpret_cast<const bf16x8*>(&cO[br * CO_RS + (ln + 1) * 40 + q * 8]);  // dx=2
            C = __builtin_amdgcn_mfma_f32_16x16x32_bf16(a0, Bv[dy * 3 + 0], C, 0, 0, 0);
            C = __builtin_amdgcn_mfma_f32_16x16x32_bf16(a1, Bv[dy * 3 + 1], C, 0, 0, 0);
            C = __builtin_amdgcn_mfma_f32_16x16x32_bf16(a2, Bv[dy * 3 + 2], C, 0, 0, 0);
        }
        float bb2 = b2[ln];
        float4 o;
        o.x = fmaxf(C[0] + bb2, 0.f);
        o.y = fmaxf(C[1] + bb2, 0.f);
        o.z = fmaxf(C[2] + bb2, 0.f);
        o.w = fmaxf(C[3] + bb2, 0.f);
        *(float4*)&c2s[ln * C2S_CS + y * C2S_RS + q * 4] = o;  // oc=ln, x=q*4+r
    };

    stage_obs(0);
    __syncthreads();
    conv1_phase(0);            // writes buffer rows 1..16 (c1 rows 0..15)
    __syncthreads();
    stage_obs(1);              // global loads overlap phase-0 MFMAs
    conv2_phase(0);            // reads rows 0..16; c2 rows 0..7
    __syncthreads();
    conv1_phase(1);            // writes buffer rows 0..15 (c1 rows 16..31)
    __syncthreads();
    conv2_phase(1);            // c2 rows 8..15
    __syncthreads();

    // pool 3x3 stride 3 -> LDS restage -> vectorized bf16 store (448 padded)
    ushort_t* ew = (ushort_t*)w1s;   // 896 B needed; w1s dead after conv1
    if (t < 400) {
        int c = t / 25, rem = t % 25, py = rem / 5, px = rem % 5;
        float s = 0.f;
        #pragma unroll
        for (int dy = 0; dy < 3; dy++)
            #pragma unroll
            for (int dx = 0; dx < 3; dx++)
                s += c2s[c * C2S_CS + (3 * py + dy) * C2S_RS + 3 * px + dx];
        ew[t] = f2bf(s * (1.f / 9.f));
    } else if (t < AK) {
        ew[t] = 0;
    }
    __syncthreads();
    if (t < 56)
        ((uint4*)(obs_emb_b + (size_t)b * AK))[t] = ((const uint4*)ew)[t];
}

// ---------------------------------------------------------------------------
// obs_part = obs_emb_b @ Wobs_b.T (MFMA), with PERMUTED column ownership:
// block (bm,bu) owns cols {g*256 + bu*32 + h*16 + ln} for all 4 gates ->
// step0 (h=c=0 LSTM cell) fused into the epilogue; step0 kernel deleted.
// ---------------------------------------------------------------------------
__global__ __launch_bounds__(256) void obs_gemm(
    const ushort_t* __restrict__ Ab, const ushort_t* __restrict__ Wob,
    ushort_t* __restrict__ outp, const float* __restrict__ bias0,
    float* __restrict__ c0_out, ushort_t* __restrict__ hb0_out)
{
    __shared__ __align__(16) ushort_t As[64 * 72];   // 9216 B
    __shared__ __align__(16) ushort_t ob[64 * 132];  // 16896 B
    const int t = threadIdx.x;
    const int bm = blockIdx.x & 63, bu = blockIdx.x >> 6;
    const int b0 = bm * 64, U0 = bu * 32;
    const int w = t >> 6, L = t & 63, q = L >> 4, ln = L & 15;
    const int m0 = w * 16;

    f32x4v acc[8];
    #pragma unroll
    for (int i = 0; i < 8; i++) acc[i] = f32x4v{0.f, 0.f, 0.f, 0.f};

    for (int kc = 0; kc < 7; kc++) {
        #pragma unroll
        for (int ii = 0; ii < 2; ii++) {
            int i = t + ii * 256;
            int row = i >> 3, c8 = i & 7;
            *(uint4*)&As[row * 72 + c8 * 8] =
                *(const uint4*)&Ab[(size_t)(b0 + row) * AK + kc * 64 + c8 * 8];
        }
        __syncthreads();
        bf16x8 a[2];
        #pragma unroll
        for (int ks = 0; ks < 2; ks++)
            a[ks] = *reinterpret_cast<const bf16x8*>(&As[(m0 + ln) * 72 + ks * 32 + q * 8]);
        #pragma unroll
        for (int ct = 0; ct < 8; ct++) {
            // ct -> (g = ct>>1, h = ct&1); col = g*256 + U0 + h*16 + ln
            int col = (ct >> 1) * 256 + U0 + (ct & 1) * 16 + ln;
            const ushort_t* wr = Wob + (size_t)col * AK + kc * 64 + q * 8;
            bf16x8 bv0 = *reinterpret_cast<const bf16x8*>(wr);
            bf16x8 bv1 = *reinterpret_cast<const bf16x8*>(wr + 32);
            acc[ct] = __builtin_amdgcn_mfma_f32_16x16x32_bf16(a[0], bv0, acc[ct], 0, 0, 0);
            acc[ct] = __builtin_amdgcn_mfma_f32_16x16x32_bf16(a[1], bv1, acc[ct], 0, 0, 0);
        }
        __syncthreads();
    }

    // fused step0: thread holds all 4 gates for (rows m0+q*4+j, unit U0+h*16+ln)
    #pragma unroll
    for (int h = 0; h < 2; h++) {
        const int u = U0 + h * 16 + ln;
        float bg[4];
        #pragma unroll
        for (int g = 0; g < 4; g++) bg[g] = bias0[g * 256 + u];
        #pragma unroll
        for (int j = 0; j < 4; j++) {
            int row = b0 + m0 + q * 4 + j;
            float pre[4];
            #pragma unroll
            for (int g = 0; g < 4; g++) pre[g] = acc[g * 2 + h][j] + bg[g];
            float c2 = sigf(pre[0]) * tanh_fast(pre[2]);
            float hv = sigf(pre[3]) * tanh_fast(c2);
            c0_out[(size_t)row * 256 + u] = c2;
            hb0_out[(size_t)row * 256 + u] = f2bf(hv);
        }
    }

    // restage C tile in LDS (bf16, local col = ct*16+ln) then permuted store
    #pragma unroll
    for (int ct = 0; ct < 8; ct++)
        #pragma unroll
        for (int j = 0; j < 4; j++)
            ob[(m0 + q * 4 + j) * 132 + ct * 16 + ln] = f2bf(acc[ct][j]);
    __syncthreads();
    #pragma unroll
    for (int p2 = 0; p2 < 4; p2++) {
        int idx = t + p2 * 256;
        int row = idx >> 4, c8 = idx & 15;
        int cl = c8 * 8;   // local col base (within one (g,h) 16-group)
        int gcol = (cl >> 5) * 256 + U0 + ((cl >> 4) & 1) * 16 + (cl & 15);
        uint4 v = *(const uint4*)&ob[row * 132 + cl];
        *(uint4*)&outp[(size_t)(b0 + row) * 1024 + gcol] = v;
    }
}

// ---------------------------------------------------------------------------
// MFMA LSTM step v2 (unchanged from R5).
// ---------------------------------------------------------------------------
template <int SAMP, int HEAD_N, int DUAL>
__global__ __launch_bounds__(512, 4) void lstm_mfma(
    const ushort_t* __restrict__ hb_in, const float* __restrict__ c_in,
    ushort_t* __restrict__ hb_out, float* __restrict__ c_out,
    const ushort_t* __restrict__ obs_part, const float* __restrict__ bias_s,
    const float* __restrict__ samp_rows, const int* __restrict__ samp_idx,
    const float* __restrict__ rp0_emb, const float* __restrict__ WsampT,
    const ushort_t* __restrict__ Wb,
    const float* __restrict__ head_w, const float* __restrict__ head_b,
    float* __restrict__ out, int out_off,
    const ushort_t* __restrict__ hb_in2, const float* __restrict__ c_in2,
    ushort_t* __restrict__ hb_out2, float* __restrict__ c_out2,
    const float* __restrict__ bias_s2, const int* __restrict__ samp_idx2,
    const float* __restrict__ head_w2, int out_off2)
{
    constexpr int PS_B = 64 * 132 * 2;   // 16896
    constexpr int CS_B = 64 * 36 * 4;    // 9216
    constexpr int EX_B = (SAMP == 2) ? (16 * 132 * 4 + 64 * 20 * 4)
                                     : (3 * 256 * 4 + 64 * 8 * 3 * 4);
    __shared__ __align__(16) char smem[PS_B + CS_B + EX_B];
    ushort_t* ps = (ushort_t*)smem;               // [64][132] bf16
    float* cs = (float*)(smem + PS_B);            // [64][36] f32
    float* hws = (float*)(smem + PS_B + CS_B);    // head weights
    float* red = (float*)(smem + PS_B + CS_B + 3 * 256 * 4);
    float* wsmp = (float*)(smem + PS_B + CS_B);   // [16][132] f32 (SAMP2)
    float* re = (float*)(smem + PS_B + CS_B + 16 * 132 * 4);  // [64][20]

    const int t = threadIdx.x;
    const int half  = DUAL ? (int)(blockIdx.x >> 9) : 0;
    const int inner = DUAL ? (int)(blockIdx.x & 511) : (int)blockIdx.x;
    const int bm = inner & 63, bu = inner >> 6;
    const int b0 = bm * 64;

    const ushort_t* hbi = (DUAL && half) ? hb_in2 : hb_in;
    const float* cip    = (DUAL && half) ? c_in2 : c_in;
    ushort_t* hbo       = (DUAL && half) ? hb_out2 : hb_out;
    float* cop          = (DUAL && half) ? c_out2 : c_out;
    const float* biasp  = (DUAL && half) ? bias_s2 : bias_s;
    const int* sidx     = (DUAL && half) ? samp_idx2 : samp_idx;
    const float* hwp    = (DUAL && half) ? head_w2 : head_w;
    const int ooff      = (DUAL && half) ? out_off2 : out_off;
    const bool do_head  = (HEAD_N > 0) && (bu == 0) && (hwp != nullptr);

    const int w = t >> 6, L = t & 63, q = L >> 4, ln = L & 15;
    const int m0 = (w & 3) * 16, wg = w >> 2;
    const int U0 = bu * 32;
    const int unit = U0 + wg * 16 + ln;

    // A fragments: direct global loads (hb L2-resident)
    bf16x8 a[8];
    {
        const ushort_t* arow = hbi + (size_t)(b0 + m0 + ln) * 256 + q * 8;
        #pragma unroll
        for (int kk = 0; kk < 8; kk++)
            a[kk] = *reinterpret_cast<const bf16x8*>(arow + kk * 32);
    }

    // cooperative staging (hidden under MFMAs)
    #pragma unroll
    for (int p = 0; p < 2; p++) {
        int idx = t + p * 512;
        int row = idx >> 4, c8 = idx & 15;
        int g = c8 >> 2, cc = (c8 & 3) * 8;
        uint4 v = *(const uint4*)&obs_part[(size_t)(b0 + row) * 1024 + g * 256 + U0 + cc];
        *(uint4*)&ps[row * 132 + c8 * 8] = v;
    }
    {
        int row = t >> 3, c4 = t & 7;
        float4 v = *(const float4*)&cip[(size_t)(b0 + row) * 256 + U0 + c4 * 4];
        *(float4*)&cs[row * 36 + c4 * 4] = v;
    }
    if (SAMP == 2) {
        int k = t >> 5, c4 = t & 31;
        float4 v = *(const float4*)&WsampT[(size_t)k * 1024 + ((c4 * 4) >> 5) * 256 + U0 + ((c4 * 4) & 31)];
        *(float4*)&wsmp[k * 132 + c4 * 4] = v;
        if (t < 256) {
            int row = t >> 2, d4 = t & 3;
            float4 e = *(const float4*)&rp0_emb[(size_t)(b0 + row) * 16 + d4 * 4];
            *(float4*)&re[row * 20 + d4 * 4] = e;
        }
    }
    if (do_head)
        for (int i = t; i < HEAD_N * 256; i += 512) hws[i] = hwp[i];

    // MFMA: 4 gates x 8 K-chunks
    f32x4v acc[4];
    #pragma unroll
    for (int g = 0; g < 4; g++) {
        f32x4v z = {0.f, 0.f, 0.f, 0.f};
        const ushort_t* wrow = Wb + (size_t)(g * 256 + unit) * 256 + q * 8;
        #pragma unroll
        for (int kk = 0; kk < 8; kk++) {
            bf16x8 bv = *reinterpret_cast<const bf16x8*>(wrow + kk * 32);
            z = __builtin_amdgcn_mfma_f32_16x16x32_bf16(a[kk], bv, z, 0, 0, 0);
        }
        acc[g] = z;
    }
    __syncthreads();   // staged data visible

    float bsv[4];
    #pragma unroll
    for (int g = 0; g < 4; g++) bsv[g] = biasp[g * 256 + unit];

    const int cc = wg * 16 + ln;
    #pragma unroll
    for (int r = 0; r < 4; r++) {
        const int row = m0 + q * 4 + r;
        const int R = b0 + row;
        float pre[4];
        #pragma unroll
        for (int g = 0; g < 4; g++)
            pre[g] = acc[g][r] + bf2f(ps[row * 132 + g * 32 + cc]) + bsv[g];
        if (SAMP == 1) {
            int si = sidx[R];
            #pragma unroll
            for (int g = 0; g < 4; g++) pre[g] += samp_rows[si * 1024 + g * 256 + unit];
        }
        if (SAMP == 2) {
            #pragma unroll
            for (int k = 0; k < 16; k++) {
                float e = re[row * 20 + k];
                #pragma unroll
                for (int g = 0; g < 4; g++) pre[g] += e * wsmp[k * 132 + g * 32 + cc];
            }
        }
        float ci = cs[row * 36 + cc];
        float c2 = sigf(pre[1]) * ci + sigf(pre[0]) * tanh_fast(pre[2]);
        float hv = sigf(pre[3]) * tanh_fast(c2);
        cs[row * 36 + cc] = c2;              // in-place (own cell)
        ps[row * 132 + cc] = f2bf(hv);       // g0 slot (own cell, already read)
    }
    __syncthreads();

    // vectorized stores
    {
        int row = t >> 3, c4 = t & 7;
        float4 v = *(const float4*)&cs[row * 36 + c4 * 4];
        *(float4*)&cop[(size_t)(b0 + row) * 256 + U0 + c4 * 4] = v;
    }
    if (t < 256) {
        int row = t >> 2, c8 = t & 3;
        uint4 v = *(const uint4*)&ps[row * 132 + c8 * 8];
        *(uint4*)&hbo[(size_t)(b0 + row) * 256 + U0 + c8 * 8] = v;
    }

    if (do_head) {
        const int row = t >> 3, seg = t & 7;
        const ushort_t* hrow = hbi + (size_t)(b0 + row) * 256 + seg * 32;
        float part[3] = {0.f, 0.f, 0.f};
        #pragma unroll
        for (int j = 0; j < 4; j++) {
            uint4 v = *(const uint4*)(hrow + j * 8);
            uint_t dw[4] = {v.x, v.y, v.z, v.w};
            #pragma unroll
            for (int d = 0; d < 4; d++) {
                float f0 = __uint_as_float(dw[d] << 16);
                float f1 = __uint_as_float(dw[d] & 0xffff0000u);
                int k = seg * 32 + j * 8 + d * 2;
                #pragma unroll
                for (int n = 0; n < HEAD_N; n++)
                    part[n] += f0 * hws[n * 256 + k] + f1 * hws[n * 256 + k + 1];
            }
        }
        #pragma unroll
        for (int n = 0; n < HEAD_N; n++) red[(row * 8 + seg) * 3 + n] = part[n];
        __syncthreads();
        if (t < 64) {
            #pragma unroll
            for (int n = 0; n < HEAD_N; n++) {
                float s = head_b[n];
                #pragma unroll
                for (int p = 0; p < 8; p++) s += red[(t * 8 + p) * 3 + n];
                out[(size_t)(b0 + t) * OUT_W + ooff + n] = s;
            }
        }
    }
}

// ---------------------------------------------------------------------------
// rp head v2: 256 blocks x 16 rows (4x parallelism vs 64-block version).
// ---------------------------------------------------------------------------
__global__ __launch_bounds__(256) void rp_head(
    const ushort_t* __restrict__ hb, const float* __restrict__ head_w,
    const float* __restrict__ head_b, const float* __restrict__ eps,
    float* __restrict__ out, int out_off, float* __restrict__ rp_store)
{
    __shared__ float hw[1024];
    __shared__ float red[16 * 16 * 4];
    __shared__ float sred[16 * 4];
    const int t = threadIdx.x;
    const int b0 = blockIdx.x * 16;
    for (int i = t; i < 1024; i += 256) hw[i] = head_w[i];
    __syncthreads();
    const int r = t >> 4, p = t & 15;   // row 0..15, 16-dim segment
    {
        const int R = b0 + r;
        float part[4] = {0.f, 0.f, 0.f, 0.f};
        const ushort_t* hr = hb + (size_t)R * 256 + p * 16;
        #pragma unroll
        for (int j = 0; j < 2; j++) {
            uint4 v = *reinterpret_cast<const uint4*>(hr + j * 8);
            uint_t dw[4] = {v.x, v.y, v.z, v.w};
            #pragma unroll
            for (int d = 0; d < 4; d++) {
                float f0 = __uint_as_float(dw[d] << 16);
                float f1 = __uint_as_float(dw[d] & 0xffff0000u);
                int k = p * 16 + j * 8 + d * 2;
                #pragma unroll
                for (int n = 0; n < 4; n++)
                    part[n] += f0 * hw[n * 256 + k] + f1 * hw[n * 256 + k + 1];
            }
        }
        #pragma unroll
        for (int n = 0; n < 4; n++) red[(r * 16 + p) * 4 + n] = part[n];
    }
    __syncthreads();
    if (t < 64) {
        int row = t >> 2, n = t & 3;
        float s = head_b[n];
        #pragma unroll
        for (int p2 = 0; p2 < 16; p2++) s += red[(row * 16 + p2) * 4 + n];
        sred[row * 4 + n] = s;
    }
    __syncthreads();
    if (t < 16) {
        const int R = b0 + t;
        float s0 = sred[t * 4 + 0], s1 = sred[t * 4 + 1];
        float s2 = sred[t * 4 + 2], s3 = sred[t * 4 + 3];
        float v0 = s0 + __expf(s2) * eps[(size_t)R * 2 + 0];
        float v1 = s1 + __expf(s3) * eps[(size_t)R * 2 + 1];
        out[(size_t)R * OUT_W + out_off + 0] = v0;
        out[(size_t)R * OUT_W + out_off + 1] = v1;
        if (rp_store) {
            rp_store[(size_t)R * 2 + 0] = v0;
            rp_store[(size_t)R * 2 + 1] = v1;
        }
    }
}

// ---------------------------------------------------------------------------
// MLP: rp0 (B x 2) -> 100 -> 100 -> rp0_emb (B x 16)
// ---------------------------------------------------------------------------
__global__ __launch_bounds__(128) void mlp_kernel(
    const float* __restrict__ rp0, const float* __restrict__ w1,
    const float* __restrict__ b1, const float* __restrict__ w2t,
    const float* __restrict__ b2, const float* __restrict__ w3t,
    const float* __restrict__ b3, float* __restrict__ emb)
{
    __shared__ float z1[100], z2[100];
    int row = blockIdx.x, t = threadIdx.x;
    float r0 = rp0[(size_t)row * 2], r1 = rp0[(size_t)row * 2 + 1];
    if (t < 100) z1[t] = tanh_fast(b1[t] + w1[t * 2] * r0 + w1[t * 2 + 1] * r1);
    __syncthreads();
    if (t < 100) {
        float s = b2[t];
        for (int k = 0; k < 100; k++) s += w2t[k * 100 + t] * z1[k];
        z2[t] = tanh_fast(s);
    }
    __syncthreads();
    if (t < 16) {
        float s = b3[t];
        for (int k = 0; k < 100; k++) s += w3t[k * 16 + t] * z2[k];
        emb[(size_t)row * 16 + t] = s;
    }
}

// ---------------------------------------------------------------------------
extern "C" void kernel_launch(void* const* d_in, const int* in_sizes, int n_in,
                              void* d_out, int out_size, void* d_ws, size_t ws_size,
                              hipStream_t stream)
{
    const float* obs        = (const float*)d_in[0];
    const int*   program_id = (const int*)d_in[1];
    const int*   shape_id   = (const int*)d_in[2];
    const int*   shape_id_0 = (const int*)d_in[3];
    const int*   shape_id_1 = (const int*)d_in[4];
    const float* eps_rp     = (const float*)d_in[5];
    const float* eps_rp0    = (const float*)d_in[6];
    const float* eps_rp1    = (const float*)d_in[7];
    const float* conv1_w    = (const float*)d_in[8];
    const float* conv1_b    = (const float*)d_in[9];
    const float* conv2_w    = (const float*)d_in[10];
    const float* conv2_b    = (const float*)d_in[11];
    const float* mlp_w1     = (const float*)d_in[12];
    const float* mlp_b1     = (const float*)d_in[13];
    const float* mlp_w2     = (const float*)d_in[14];
    const float* mlp_b2     = (const float*)d_in[15];
    const float* mlp_w3     = (const float*)d_in[16];
    const float* mlp_b3     = (const float*)d_in[17];
    const float* W_ih       = (const float*)d_in[18];
    const float* b_ih       = (const float*)d_in[19];
    const float* W_hh       = (const float*)d_in[20];
    const float* b_hh       = (const float*)d_in[21];
    const float* addr_emb   = (const float*)d_in[22];
    const float* pid_emb    = (const float*)d_in[23];
    const float* sid_emb    = (const float*)d_in[24];
    const float* pid_ext_w  = (const float*)d_in[25];
    const float* pid_ext_b  = (const float*)d_in[26];
    const float* sid_ext_w  = (const float*)d_in[27];
    const float* sid_ext_b  = (const float*)d_in[28];
    const float* rp_ext_w   = (const float*)d_in[29];
    const float* rp_ext_b   = (const float*)d_in[30];
    float* out = (float*)d_out;

    // workspace layout (float slots, 16B-aligned chunks)
    float* ws = (float*)d_ws;
    size_t off = 0;
    float* W_ih_T   = ws + off; off += 432 * 1024;              // fp32
    ushort_t* Wb    = (ushort_t*)(ws + off); off += 131072;     // bf16 1024x256
    float* bias_all = ws + off; off += 7 * 1024;
    float* pid_rows = ws + off; off += 3 * 1024;
    float* sid_rows = ws + off; off += 2 * 1024;
    ushort_t* obs_emb_b = (ushort_t*)(ws + off); off += (size_t)BATCH * AK / 2;  // bf16 Bx448
    ushort_t* Wobs_b    = (ushort_t*)(ws + off); off += (size_t)1024 * AK / 2;   // bf16 1024x448
    ushort_t* obs_part = (ushort_t*)(ws + off); off += (size_t)BATCH * 512;  // bf16 Bx1024
    ushort_t* hb0 = (ushort_t*)(ws + off); off += (size_t)BATCH * 128;      // bf16 Bx256
    ushort_t* hbA = (ushort_t*)(ws + off); off += (size_t)BATCH * 128;
    ushort_t* hbB = (ushort_t*)(ws + off); off += (size_t)BATCH * 128;
    ushort_t* hbC = (ushort_t*)(ws + off); off += (size_t)BATCH * 128;
    ushort_t* hbA2 = (ushort_t*)(ws + off); off += (size_t)BATCH * 128;
    ushort_t* hbB2 = (ushort_t*)(ws + off); off += (size_t)BATCH * 128;
    float* c0 = ws + off; off += (size_t)BATCH * 256;
    float* cA = ws + off; off += (size_t)BATCH * 256;
    float* cB = ws + off; off += (size_t)BATCH * 256;
    float* cC = ws + off; off += (size_t)BATCH * 256;
    float* cD = ws + off; off += (size_t)BATCH * 256;   // dump for terminal c
    float* cA2 = ws + off; off += (size_t)BATCH * 256;
    float* rp0      = ws + off; off += (size_t)BATCH * 2;
    float* rp0_emb  = ws + off; off += (size_t)BATCH * 16;
    float* w2t = ws + off; off += 10000;
    float* w3t = ws + off; off += 1600;
    float* w1pp = ws + off; off += 384;
    ushort_t* Btg = (ushort_t*)(ws + off); off += 2304;  // 4608 bf16
    float* WsampT = W_ih_T + (size_t)400 * 1024;  // rows 400..415 of W_ih_T (fp32)

    prep_kernel<<<68, 256, 0, stream>>>(W_ih, W_hh, b_ih, b_hh, addr_emb,
                                        pid_emb, sid_emb, mlp_w2, mlp_w3,
                                        conv1_w, conv1_b, conv2_w,
                                        W_ih_T, Wb, bias_all, pid_rows,
                                        sid_rows, w2t, w3t, w1pp, Btg, Wobs_b);
    conv_kernel<<<BATCH, 512, 0, stream>>>(obs, w1pp, Btg, conv2_b, obs_emb_b);
    // obs GEMM with fused step0 (aid 0): writes obs_part, c0, hb0
    obs_gemm<<<512, 256, 0, stream>>>(obs_emb_b, Wobs_b, obs_part,
                                      bias_all + 0 * 1024, c0, hb0);

    // merged step1 (aid 1, head pid on h0 -> cols 0..2) + step1b (aid 2, no head)
    lstm_mfma<1, 3, 1><<<1024, 512, 0, stream>>>(
        hb0, c0, hbA, cA, obs_part, bias_all + 1 * 1024,
        pid_rows, program_id, nullptr, nullptr, Wb,
        pid_ext_w, pid_ext_b, out, 0,
        hb0, c0, hbA2, cA2, bias_all + 3 * 1024, program_id, nullptr, 0);
    // merged step2 (aid 4, head sid on h1 -> cols 3..4) + step2b (aid 3, head sid0 -> cols 7..8)
    lstm_mfma<1, 2, 1><<<1024, 512, 0, stream>>>(
        hbA, cA, hbB, cD, obs_part, bias_all + 2 * 1024,
        sid_rows, shape_id, nullptr, nullptr, Wb,
        sid_ext_w, sid_ext_b, out, 3,
        hbA2, cA2, hbB2, cB, bias_all + 4 * 1024, shape_id_0, sid_ext_w, 7);
    // rp_b0 head on h2 (hbB) -> cols 5..6
    rp_head<<<256, 256, 0, stream>>>(hbB, rp_ext_w, rp_ext_b, eps_rp, out, 5, nullptr);
    // step3b (aid 5): hbB2,cB -> hbC,cC; samp sid[shape_id_1]; head = sid1(2) -> cols 9..10
    lstm_mfma<1, 2, 0><<<512, 512, 0, stream>>>(
        hbB2, cB, hbC, cC, obs_part, bias_all + 5 * 1024,
        sid_rows, shape_id_1, nullptr, nullptr, Wb,
        sid_ext_w, sid_ext_b, out, 9,
        nullptr, nullptr, nullptr, nullptr, nullptr, nullptr, nullptr, 0);
    // rp0 head on h3b (hbC) -> cols 11..12, store rp0
    rp_head<<<256, 256, 0, stream>>>(hbC, rp_ext_w, rp_ext_b, eps_rp0, out, 11, rp0);
    mlp_kernel<<<BATCH, 128, 0, stream>>>(rp0, mlp_w1, mlp_b1, w2t, mlp_b2,
                                          w3t, mlp_b3, rp0_emb);
    // step4b (aid 6): hbC,cC -> hbB,cD; samp = rp0_emb @ WsampT; no head
    lstm_mfma<2, 0, 0><<<512, 512, 0, stream>>>(
        hbC, cC, hbB, cD, obs_part, bias_all + 6 * 1024,
        nullptr, nullptr, rp0_emb, WsampT, Wb,
        nullptr, nullptr, out, 0,
        nullptr, nullptr, nullptr, nullptr, nullptr, nullptr, nullptr, 0);
    // rp1 head on h4b (hbB) -> cols 13..14
    rp_head<<<256, 256, 0, stream>>>(hbB, rp_ext_w, rp_ext_b, eps_rp1, out, 13, nullptr);
}

// Round 7
// 382.281 us; speedup vs baseline: 1.3536x; 1.1111x over previous
//
#include <hip/hip_runtime.h>
#include <hip/hip_bf16.h>
#include <math.h>

#define BATCH 4096
#define HID 256
#define OUT_W 15
#define AK 448   // padded K for obs GEMM (400 valid + 48 zeros)

typedef unsigned short ushort_t;
typedef unsigned int uint_t;

using bf16x8 = __attribute__((ext_vector_type(8))) short;
using f32x4v = __attribute__((ext_vector_type(4))) float;
using f32x2 = __attribute__((ext_vector_type(2))) float;

__device__ __forceinline__ float sigf(float x) { return 1.0f / (1.0f + __expf(-x)); }
__device__ __forceinline__ float tanh_fast(float x) { return 1.0f - 2.0f / (__expf(2.0f * x) + 1.0f); }
__device__ __forceinline__ float bf2f(ushort_t u) { return __uint_as_float(((uint_t)u) << 16); }
__device__ __forceinline__ ushort_t f2bf(float x) {
    uint_t b = __float_as_uint(x);
    return (ushort_t)((b + 0x7fffu + ((b >> 16) & 1u)) >> 16);
}

// ---------------------------------------------------------------------------
// Prep (68 blocks): unchanged from R6.
// ---------------------------------------------------------------------------
__global__ __launch_bounds__(256) void prep_kernel(
    const float* __restrict__ W_ih, const float* __restrict__ W_hh,
    const float* __restrict__ b_ih, const float* __restrict__ b_hh,
    const float* __restrict__ addr_emb, const float* __restrict__ pid_emb,
    const float* __restrict__ sid_emb,
    const float* __restrict__ mlp_w2, const float* __restrict__ mlp_w3,
    const float* __restrict__ conv1_w, const float* __restrict__ conv1_b,
    const float* __restrict__ conv2_w,
    float* __restrict__ W_ih_T, ushort_t* __restrict__ Wb,
    float* __restrict__ bias_all, float* __restrict__ pid_rows,
    float* __restrict__ sid_rows, float* __restrict__ w2t, float* __restrict__ w3t,
    float* __restrict__ w1pp, ushort_t* __restrict__ Btg,
    ushort_t* __restrict__ Wobs_b)
{
    int blk = blockIdx.x, t = threadIdx.x;
    if (blk < 16) {
        // W_ih tile (64 cols j0, k 384..447) -> W_ih_T (WsampT source)
        __shared__ float tile[64][65];
        int j0 = blk * 64;
        int k0 = 384;
        for (int i = t; i < 4096; i += 256) {
            int r = i >> 6, c = i & 63;
            int k = k0 + c;
            tile[r][c] = (k < 432) ? W_ih[(size_t)(j0 + r) * 432 + k] : 0.f;
        }
        __syncthreads();
        for (int i = t; i < 4096; i += 256) {
            int r = i >> 6, c = i & 63;
            int k = k0 + r;
            if (k < 432) W_ih_T[(size_t)k * 1024 + j0 + c] = tile[c][r];
        }
    } else if (blk == 16) {
        const int aids[7] = {0, 1, 4, 2, 3, 5, 6};
        for (int s = 0; s < 7; s++) {
            int aid = aids[s];
            for (int j = t; j < 1024; j += 256) {
                float v = b_ih[j] + b_hh[j];
                #pragma unroll
                for (int k = 0; k < 16; k++)
                    v += addr_emb[aid * 16 + k] * W_ih[(size_t)j * 432 + 416 + k];
                bias_all[s * 1024 + j] = v;
            }
        }
    } else if (blk == 17) {
        for (int p = 0; p < 3; p++)
            for (int j = t; j < 1024; j += 256) {
                float v = 0.f;
                #pragma unroll
                for (int k = 0; k < 16; k++)
                    v += pid_emb[p * 16 + k] * W_ih[(size_t)j * 432 + 400 + k];
                pid_rows[p * 1024 + j] = v;
            }
        for (int p = 0; p < 2; p++)
            for (int j = t; j < 1024; j += 256) {
                float v = 0.f;
                #pragma unroll
                for (int k = 0; k < 16; k++)
                    v += sid_emb[p * 16 + k] * W_ih[(size_t)j * 432 + 400 + k];
                sid_rows[p * 1024 + j] = v;
            }
    } else if (blk == 18) {
        for (int i = t; i < 10000; i += 256) {
            int o = i / 100, k = i % 100;
            w2t[k * 100 + o] = mlp_w2[i];
        }
        for (int i = t; i < 1600; i += 256) {
            int o = i / 100, k = i % 100;
            w3t[k * 16 + o] = mlp_w3[i];
        }
    } else if (blk == 19) {
        // w1pp[icq][i][k][2]: pair halves = ics (icq*8+i, icq*8+4+i)
        for (int i = t; i < 320; i += 256) {
            int half = i & 1, idx = i >> 1;
            int k = idx % 10, pr = idx / 10;
            int icq = pr >> 2, i2 = pr & 3;
            int ic = icq * 8 + i2 + half * 4;
            w1pp[i] = (k < 9) ? conv1_w[ic * 9 + k] : conv1_b[ic];
        }
        for (int i = t; i < 4608; i += 256) {
            int tap = i >> 9;
            int rem = i & 511;
            int oc = rem >> 5, ic = rem & 31;
            Btg[i] = f2bf(conv2_w[(size_t)(oc * 32 + ic) * 9 + tap]);
        }
    } else if (blk < 36) {
        int seg = blk - 20;  // 0..15
        for (int i = seg * 16384 + t; i < (seg + 1) * 16384; i += 256)
            Wb[i] = f2bf(W_hh[i]);
    } else {
        int col0 = (blk - 36) * 32;
        for (int i = t; i < 32 * AK; i += 256) {
            int c = col0 + i / AK, k = i % AK;
            Wobs_b[(size_t)c * AK + k] = (k < 400) ? f2bf(W_ih[(size_t)c * 432 + k]) : (ushort_t)0;
        }
    }
}

// ---------------------------------------------------------------------------
// Conv encoder v8 (unchanged from R6).
// ---------------------------------------------------------------------------
#define CE_RS 640
#define CO_RS 680
#define SM2S 72
#define C2S_CS 324
#define C2S_RS 20
__global__ __launch_bounds__(512, 4) void conv_kernel(
    const float* __restrict__ obs, const float* __restrict__ w1pp,
    const ushort_t* __restrict__ Btg, const float* __restrict__ b2,
    ushort_t* __restrict__ obs_emb_b)
{
    __shared__ __align__(16) ushort_t cE[17 * CE_RS];
    __shared__ __align__(16) ushort_t cO[17 * CO_RS];
    __shared__ __align__(16) float c2s[16 * C2S_CS];
    __shared__ __align__(16) float sm2[33 * SM2S];
    __shared__ __align__(16) float w1s[320];
    const int b = blockIdx.x, t = threadIdx.x;
    const float* og = obs + (size_t)b * 4096;

    const int w = t >> 6, L = t & 63, q = L >> 4, ln = L & 15;

    {
        uint_t* zE = (uint_t*)cE;
        uint_t* zO = (uint_t*)cO;
        for (int i = t; i < CE_RS / 2; i += 512) zE[i] = 0;
        for (int i = t; i < CO_RS / 2; i += 512) zO[i] = 0;
        if (t < 320) {
            int row = (t / 20) + 1, d = t % 20;
            zO[row * (CO_RS / 2) + d] = 0;
        }
    }
    if (t < 80) ((float4*)w1s)[t] = ((const float4*)w1pp)[t];
    if (t < 33) {
        int sw = (t >> 1) & 1;
        sm2[t * SM2S + sw * 4 + 3] = 0.f;
    }

    auto stage_obs = [&](int ph) {
        for (int i = t; i < 33 * 16; i += 512) {
            int row = i >> 4, c4 = i & 15;
            int sw = (row >> 1) & 1;
            int orow = 32 * ph - 1 + row;
            float4 v = float4{0.f, 0.f, 0.f, 0.f};
            if (orow >= 0) v = ((const float4*)(og + (size_t)orow * 64))[c4];
            *(float4*)&sm2[row * SM2S + ((1 + c4) ^ sw) * 4] = v;
        }
    };

    auto conv1_phase = [&](int ph) {
        const int r = t >> 5, g = (t >> 2) & 7, icq = t & 3;
        const int brow = ph ? r : (r + 1);
        float Pt[3][12];
        #pragma unroll
        for (int d = 0; d < 3; d++) {
            int row = 2 * r + d;
            int sw = (row >> 1) & 1;
            const float* base = &sm2[row * SM2S];
            #pragma unroll
            for (int j4 = 0; j4 < 3; j4++) {
                float4 v = *(const float4*)(base + ((2 * g + j4) ^ sw) * 4);
                Pt[d][j4 * 4 + 0] = v.x; Pt[d][j4 * 4 + 1] = v.y;
                Pt[d][j4 * 4 + 2] = v.z; Pt[d][j4 * 4 + 3] = v.w;
            }
        }
        const float* wpbase = &w1s[icq * 80];
        #pragma unroll
        for (int p = 0; p < 4; p++) {
            f32x2 pbc[9];
            #pragma unroll
            for (int d = 0; d < 3; d++)
                #pragma unroll
                for (int dx = 0; dx < 3; dx++) {
                    float v = Pt[d][2 * p + 3 + dx];
                    pbc[d * 3 + dx] = f32x2{v, v};
                }
            f32x2 sall[4];
            #pragma unroll
            for (int i = 0; i < 4; i++) {
                const float* wp = wpbase + i * 20;
                float4 wv0 = *(const float4*)(wp);
                float4 wv1 = *(const float4*)(wp + 4);
                float4 wv2 = *(const float4*)(wp + 8);
                float4 wv3 = *(const float4*)(wp + 12);
                float4 wv4 = *(const float4*)(wp + 16);
                f32x2 W2[10] = {f32x2{wv0.x, wv0.y}, f32x2{wv0.z, wv0.w},
                                f32x2{wv1.x, wv1.y}, f32x2{wv1.z, wv1.w},
                                f32x2{wv2.x, wv2.y}, f32x2{wv2.z, wv2.w},
                                f32x2{wv3.x, wv3.y}, f32x2{wv3.z, wv3.w},
                                f32x2{wv4.x, wv4.y}, f32x2{wv4.z, wv4.w}};
                f32x2 a2 = W2[9];
                #pragma unroll
                for (int k = 0; k < 9; k++)
                    a2 = __builtin_elementwise_fma(pbc[k], W2[k], a2);
                a2 = __builtin_elementwise_max(a2, f32x2{0.f, 0.f});
                sall[i] = a2;
            }
            uint_t d0, d1, d2, d3;
            asm("v_cvt_pk_bf16_f32 %0, %1, %2" : "=v"(d0) : "v"(sall[0].x), "v"(sall[1].x));
            asm("v_cvt_pk_bf16_f32 %0, %1, %2" : "=v"(d1) : "v"(sall[2].x), "v"(sall[3].x));
            asm("v_cvt_pk_bf16_f32 %0, %1, %2" : "=v"(d2) : "v"(sall[0].y), "v"(sall[1].y));
            asm("v_cvt_pk_bf16_f32 %0, %1, %2" : "=v"(d3) : "v"(sall[2].y), "v"(sall[3].y));
            int c = 4 * g + p;
            ushort_t* dst = (c & 1)
                ? &cO[brow * CO_RS + ((c + 1) >> 1) * 40 + icq * 8]
                : &cE[brow * CE_RS + (c >> 1) * 40 + icq * 8];
            *(uint4*)dst = uint4{d0, d1, d2, d3};
        }
    };

    auto conv2_phase = [&](int ph) {
        bf16x8 Bv[9];
        #pragma unroll
        for (int tap = 0; tap < 9; tap++)
            Bv[tap] = *reinterpret_cast<const bf16x8*>(&Btg[(tap * 16 + ln) * 32 + q * 8]);
        const int y = 8 * ph + w;
        f32x4v C = {0.f, 0.f, 0.f, 0.f};
        #pragma unroll
        for (int dy = 0; dy < 3; dy++) {
            int br = 2 * y + dy;
            if (br >= 17) br -= 17;
            bf16x8 a0 = *reinterpret_cast<const bf16x8*>(&cO[br * CO_RS + ln * 40 + q * 8]);
            bf16x8 a1 = *reinterpret_cast<const bf16x8*>(&cE[br * CE_RS + ln * 40 + q * 8]);
            bf16x8 a2 = *reinterpret_cast<const bf16x8*>(&cO[br * CO_RS + (ln + 1) * 40 + q * 8]);
            C = __builtin_amdgcn_mfma_f32_16x16x32_bf16(a0, Bv[dy * 3 + 0], C, 0, 0, 0);
            C = __builtin_amdgcn_mfma_f32_16x16x32_bf16(a1, Bv[dy * 3 + 1], C, 0, 0, 0);
            C = __builtin_amdgcn_mfma_f32_16x16x32_bf16(a2, Bv[dy * 3 + 2], C, 0, 0, 0);
        }
        float bb2 = b2[ln];
        float4 o;
        o.x = fmaxf(C[0] + bb2, 0.f);
        o.y = fmaxf(C[1] + bb2, 0.f);
        o.z = fmaxf(C[2] + bb2, 0.f);
        o.w = fmaxf(C[3] + bb2, 0.f);
        *(float4*)&c2s[ln * C2S_CS + y * C2S_RS + q * 4] = o;
    };

    stage_obs(0);
    __syncthreads();
    conv1_phase(0);
    __syncthreads();
    stage_obs(1);
    conv2_phase(0);
    __syncthreads();
    conv1_phase(1);
    __syncthreads();
    conv2_phase(1);
    __syncthreads();

    ushort_t* ew = (ushort_t*)w1s;
    if (t < 400) {
        int c = t / 25, rem = t % 25, py = rem / 5, px = rem % 5;
        float s = 0.f;
        #pragma unroll
        for (int dy = 0; dy < 3; dy++)
            #pragma unroll
            for (int dx = 0; dx < 3; dx++)
                s += c2s[c * C2S_CS + (3 * py + dy) * C2S_RS + 3 * px + dx];
        ew[t] = f2bf(s * (1.f / 9.f));
    } else if (t < AK) {
        ew[t] = 0;
    }
    __syncthreads();
    if (t < 56)
        ((uint4*)(obs_emb_b + (size_t)b * AK))[t] = ((const uint4*)ew)[t];
}

// ---------------------------------------------------------------------------
// obs_part = obs_emb_b @ Wobs_b.T (MFMA), standard [row][1024] layout.
// ---------------------------------------------------------------------------
__global__ __launch_bounds__(256) void obs_gemm(
    const ushort_t* __restrict__ Ab, const ushort_t* __restrict__ Wob,
    ushort_t* __restrict__ outp)
{
    __shared__ __align__(16) ushort_t As[64 * 72];
    __shared__ __align__(16) ushort_t ob[64 * 132];
    const int t = threadIdx.x;
    const int bm = blockIdx.x & 63, bu = blockIdx.x >> 6;
    const int b0 = bm * 64, n0 = bu * 128;
    const int w = t >> 6, L = t & 63, q = L >> 4, ln = L & 15;
    const int m0 = w * 16;

    f32x4v acc[8];
    #pragma unroll
    for (int i = 0; i < 8; i++) acc[i] = f32x4v{0.f, 0.f, 0.f, 0.f};

    for (int kc = 0; kc < 7; kc++) {
        #pragma unroll
        for (int ii = 0; ii < 2; ii++) {
            int i = t + ii * 256;
            int row = i >> 3, c8 = i & 7;
            *(uint4*)&As[row * 72 + c8 * 8] =
                *(const uint4*)&Ab[(size_t)(b0 + row) * AK + kc * 64 + c8 * 8];
        }
        __syncthreads();
        bf16x8 a[2];
        #pragma unroll
        for (int ks = 0; ks < 2; ks++)
            a[ks] = *reinterpret_cast<const bf16x8*>(&As[(m0 + ln) * 72 + ks * 32 + q * 8]);
        #pragma unroll
        for (int ct = 0; ct < 8; ct++) {
            const ushort_t* wr = Wob + (size_t)(n0 + ct * 16 + ln) * AK + kc * 64 + q * 8;
            bf16x8 bv0 = *reinterpret_cast<const bf16x8*>(wr);
            bf16x8 bv1 = *reinterpret_cast<const bf16x8*>(wr + 32);
            acc[ct] = __builtin_amdgcn_mfma_f32_16x16x32_bf16(a[0], bv0, acc[ct], 0, 0, 0);
            acc[ct] = __builtin_amdgcn_mfma_f32_16x16x32_bf16(a[1], bv1, acc[ct], 0, 0, 0);
        }
        __syncthreads();
    }
    #pragma unroll
    for (int ct = 0; ct < 8; ct++)
        #pragma unroll
        for (int j = 0; j < 4; j++)
            ob[(m0 + q * 4 + j) * 132 + ct * 16 + ln] = f2bf(acc[ct][j]);
    __syncthreads();
    #pragma unroll
    for (int p2 = 0; p2 < 4; p2++) {
        int idx = t + p2 * 256;
        int row = idx >> 4, c8 = idx & 15;
        uint4 v = *(const uint4*)&ob[row * 132 + c8 * 8];
        *(uint4*)&outp[(size_t)(b0 + row) * 1024 + n0 + c8 * 8] = v;
    }
}

// ---------------------------------------------------------------------------
// Heads (block-local, 16 rows; 512 threads).
// ---------------------------------------------------------------------------
template <int N>
__device__ __forceinline__ void head_logits_f(
    const ushort_t* hsrc, const float* __restrict__ hw, const float* __restrict__ hb,
    int off, float* red, float* __restrict__ out, int b0, int t)
{
    const int row = t >> 5, seg = t & 31;
    float part[N] = {};
    const ushort_t* hr = hsrc + row * 272 + seg * 8;
    #pragma unroll
    for (int e = 0; e < 8; e++) {
        float hv = bf2f(hr[e]);
        #pragma unroll
        for (int m = 0; m < N; m++) part[m] += hv * hw[m * 256 + seg * 8 + e];
    }
    #pragma unroll
    for (int m = 0; m < N; m++) red[(row * 32 + seg) * 4 + m] = part[m];
    __syncthreads();
    if (t < 16 * N) {
        int r2 = t / N, m = t % N;
        float s = hb[m];
        for (int p = 0; p < 32; p++) s += red[(r2 * 32 + p) * 4 + m];
        out[(size_t)(b0 + r2) * OUT_W + off + m] = s;
    }
    __syncthreads();
}

__device__ __forceinline__ void head_rp_f(
    const ushort_t* hsrc, const float* __restrict__ hw, const float* __restrict__ hb,
    const float* __restrict__ eps, int off, float* red, float* hdr,
    float* __restrict__ out, float* rp0s, int b0, int t)
{
    const int row = t >> 5, seg = t & 31;
    float part[4] = {0.f, 0.f, 0.f, 0.f};
    const ushort_t* hr = hsrc + row * 272 + seg * 8;
    #pragma unroll
    for (int e = 0; e < 8; e++) {
        float hv = bf2f(hr[e]);
        #pragma unroll
        for (int m = 0; m < 4; m++) part[m] += hv * hw[m * 256 + seg * 8 + e];
    }
    #pragma unroll
    for (int m = 0; m < 4; m++) red[(row * 32 + seg) * 4 + m] = part[m];
    __syncthreads();
    if (t < 64) {
        int r2 = t >> 2, m = t & 3;
        float s = hb[m];
        for (int p = 0; p < 32; p++) s += red[(r2 * 32 + p) * 4 + m];
        hdr[t] = s;
    }
    __syncthreads();
    if (t < 16) {
        int R = b0 + t;
        float v0 = hdr[t * 4 + 0] + __expf(hdr[t * 4 + 2]) * eps[(size_t)R * 2 + 0];
        float v1 = hdr[t * 4 + 1] + __expf(hdr[t * 4 + 3]) * eps[(size_t)R * 2 + 1];
        out[(size_t)R * OUT_W + off + 0] = v0;
        out[(size_t)R * OUT_W + off + 1] = v1;
        if (rp0s) { rp0s[t * 2 + 0] = v0; rp0s[t * 2 + 1] = v1; }
    }
    __syncthreads();
}

// ---------------------------------------------------------------------------
// LSTM chain: the ENTIRE post-GEMM network in ONE kernel.
// 256 blocks x 512 thr; block owns batch rows b0..b0+15 -> every dependency
// (next step's A, heads, MLP, samp2) is block-local; h lives in LDS, c in
// registers; only the 15 output cols are written to global.
// Steps: s0(epi only) -> s1/s1b(SHARED GEMM, bias differs) -> s2 -> s2b ->
// s3b -> MLP -> s4b, with heads interleaved. 5 GEMMs total.
// ---------------------------------------------------------------------------
__global__ __launch_bounds__(512, 2) void lstm_chain(
    const ushort_t* __restrict__ obs_part, const float* __restrict__ bias_all,
    const float* __restrict__ pid_rows, const float* __restrict__ sid_rows,
    const int* __restrict__ program_id, const int* __restrict__ shape_id,
    const int* __restrict__ shape_id_0, const int* __restrict__ shape_id_1,
    const ushort_t* __restrict__ Wb, const float* __restrict__ WsampT,
    const float* __restrict__ pid_ext_w, const float* __restrict__ pid_ext_b,
    const float* __restrict__ sid_ext_w, const float* __restrict__ sid_ext_b,
    const float* __restrict__ rp_ext_w, const float* __restrict__ rp_ext_b,
    const float* __restrict__ eps_rp, const float* __restrict__ eps_rp0,
    const float* __restrict__ eps_rp1,
    const float* __restrict__ mlp_w1, const float* __restrict__ mlp_b1,
    const float* __restrict__ w2t, const float* __restrict__ mlp_b2,
    const float* __restrict__ w3t, const float* __restrict__ mlp_b3,
    float* __restrict__ out)
{
    __shared__ __align__(16) ushort_t ps_t[1024 * 20];   // obs_part^T [col][16rows+pad] 40960 B
    __shared__ __align__(16) ushort_t hbuf[3][16 * 272]; // h buffers, stride 272  26112 B
    __shared__ float red[16 * 32 * 4];                   // 8192 B
    __shared__ float hdr[64];
    __shared__ float z1s[16][104], z2s[16][104];         // 13312 B
    __shared__ float emb_s[16][20];
    __shared__ float rp0s[16][2];
    __shared__ int sidx_s[4][16];

    const int t = threadIdx.x;
    const int b0 = blockIdx.x * 16;
    const int w = t >> 6, L = t & 63, q = L >> 4, ln = L & 15;
    const int U = w * 32;

    if (t < 64) {
        int tbl = t >> 4, r = t & 15;
        const int* src = (tbl == 0) ? program_id : (tbl == 1) ? shape_id
                       : (tbl == 2) ? shape_id_0 : shape_id_1;
        sidx_s[tbl][r] = src[b0 + r];
    }
    // stage obs_part transposed: [row][col] -> ps_t[col*20 + row]
    for (int i = t; i < 2048; i += 512) {
        int row = i >> 7, c8 = (i & 127) * 8;
        uint4 v = *(const uint4*)&obs_part[(size_t)(b0 + row) * 1024 + c8];
        uint_t dw[4] = {v.x, v.y, v.z, v.w};
        #pragma unroll
        for (int k = 0; k < 4; k++) {
            ps_t[(c8 + 2 * k) * 20 + row] = (ushort_t)(dw[k] & 0xffffu);
            ps_t[(c8 + 2 * k + 1) * 20 + row] = (ushort_t)(dw[k] >> 16);
        }
    }
    __syncthreads();

    float cA[8], cB[8];       // cell state, [j*2+h]; A-path / B-path
    f32x4v acc[4][2];         // GEMM result [gate][h]

    // ---- s0 (bias 0): h=c=0 -> h0 (hbuf0), cA=cB=c0
    #pragma unroll
    for (int h = 0; h < 2; h++) {
        const int unit = U + h * 16 + ln;
        float pre[4][4];
        #pragma unroll
        for (int g = 0; g < 4; g++) {
            uint2 pv = *(const uint2*)&ps_t[(g * 256 + unit) * 20 + q * 4];
            float bg = bias_all[g * 256 + unit];
            pre[g][0] = bf2f((ushort_t)(pv.x & 0xffffu)) + bg;
            pre[g][1] = bf2f((ushort_t)(pv.x >> 16)) + bg;
            pre[g][2] = bf2f((ushort_t)(pv.y & 0xffffu)) + bg;
            pre[g][3] = bf2f((ushort_t)(pv.y >> 16)) + bg;
        }
        #pragma unroll
        for (int j = 0; j < 4; j++) {
            float c2 = sigf(pre[0][j]) * tanh_fast(pre[2][j]);
            float hv = sigf(pre[3][j]) * tanh_fast(c2);
            cA[j * 2 + h] = c2; cB[j * 2 + h] = c2;
            hbuf[0][(q * 4 + j) * 272 + unit] = f2bf(hv);
        }
    }
    __syncthreads();

    auto gemm = [&](int src) {
        bf16x8 a[8];
        #pragma unroll
        for (int kk = 0; kk < 8; kk++)
            a[kk] = *reinterpret_cast<const bf16x8*>(&hbuf[src][ln * 272 + kk * 32 + q * 8]);
        #pragma unroll
        for (int g = 0; g < 4; g++)
            #pragma unroll
            for (int h = 0; h < 2; h++) {
                f32x4v z = {0.f, 0.f, 0.f, 0.f};
                const ushort_t* wr = Wb + (size_t)(g * 256 + U + h * 16 + ln) * 256 + q * 8;
                #pragma unroll
                for (int kk = 0; kk < 8; kk++)
                    z = __builtin_amdgcn_mfma_f32_16x16x32_bf16(a[kk],
                        *reinterpret_cast<const bf16x8*>(wr + kk * 32), z, 0, 0, 0);
                acc[g][h] = z;
            }
    };

    auto epi = [&](int bi, const float* samp, int tbl, int dst, float* cr) {
        #pragma unroll
        for (int h = 0; h < 2; h++) {
            const int unit = U + h * 16 + ln;
            float pre[4][4];
            #pragma unroll
            for (int g = 0; g < 4; g++) {
                uint2 pv = *(const uint2*)&ps_t[(g * 256 + unit) * 20 + q * 4];
                float bg = bias_all[bi * 1024 + g * 256 + unit];
                pre[g][0] = acc[g][h][0] + bf2f((ushort_t)(pv.x & 0xffffu)) + bg;
                pre[g][1] = acc[g][h][1] + bf2f((ushort_t)(pv.x >> 16)) + bg;
                pre[g][2] = acc[g][h][2] + bf2f((ushort_t)(pv.y & 0xffffu)) + bg;
                pre[g][3] = acc[g][h][3] + bf2f((ushort_t)(pv.y >> 16)) + bg;
            }
            #pragma unroll
            for (int j = 0; j < 4; j++) {
                int si = sidx_s[tbl][q * 4 + j];
                #pragma unroll
                for (int g = 0; g < 4; g++)
                    pre[g][j] += samp[(size_t)si * 1024 + g * 256 + unit];
            }
            #pragma unroll
            for (int j = 0; j < 4; j++) {
                float ci = cr[j * 2 + h];
                float c2 = sigf(pre[1][j]) * ci + sigf(pre[0][j]) * tanh_fast(pre[2][j]);
                float hv = sigf(pre[3][j]) * tanh_fast(c2);
                cr[j * 2 + h] = c2;
                hbuf[dst][(q * 4 + j) * 272 + unit] = f2bf(hv);
            }
        }
    };

    // pid logits on h0 -> cols 0..2
    head_logits_f<3>(hbuf[0], pid_ext_w, pid_ext_b, 0, red, out, b0, t);

    // s1 (bias1) + s1b (bias3): SAME GEMM (same h0, same W_hh, same samp)
    gemm(0);
    epi(1, pid_rows, 0, 1, cA);    // h1 -> buf1
    epi(3, pid_rows, 0, 2, cB);    // h1b -> buf2
    __syncthreads();

    // sid logits on h1 -> cols 3..4
    head_logits_f<2>(hbuf[1], sid_ext_w, sid_ext_b, 3, red, out, b0, t);

    // s2 (bias2, sid[shape_id]): h1 -> h2 (buf0); cA becomes dump
    gemm(1);
    epi(2, sid_rows, 1, 0, cA);
    __syncthreads();

    // rp_b0 on h2 -> cols 5..6
    head_rp_f(hbuf[0], rp_ext_w, rp_ext_b, eps_rp, 5, red, hdr, out, nullptr, b0, t);

    // s2b (bias4, sid[shape_id_0]): h1b -> h2b (buf1)
    gemm(2);
    epi(4, sid_rows, 2, 1, cB);
    __syncthreads();

    // sid0 on h1b -> 7..8 ; sid1 on h2b -> 9..10
    head_logits_f<2>(hbuf[2], sid_ext_w, sid_ext_b, 7, red, out, b0, t);
    head_logits_f<2>(hbuf[1], sid_ext_w, sid_ext_b, 9, red, out, b0, t);

    // s3b (bias5, sid[shape_id_1]): h2b -> h3b (buf2)
    gemm(1);
    epi(5, sid_rows, 3, 2, cB);
    __syncthreads();

    // rp0 on h3b -> cols 11..12 (+ rp0s for MLP)
    head_rp_f(hbuf[2], rp_ext_w, rp_ext_b, eps_rp0, 11, red, hdr, out, &rp0s[0][0], b0, t);

    // MLP: rp0 -> 100 -> 100 -> emb (block-local, 16 rows)
    for (int i = t; i < 1600; i += 512) {
        int row = i / 100, j = i % 100;
        z1s[row][j] = tanh_fast(mlp_b1[j] + mlp_w1[j * 2] * rp0s[row][0]
                                          + mlp_w1[j * 2 + 1] * rp0s[row][1]);
    }
    __syncthreads();
    for (int i = t; i < 1600; i += 512) {
        int row = i / 100, j = i % 100;
        float s = mlp_b2[j];
        for (int k = 0; k < 100; k++) s += w2t[k * 100 + j] * z1s[row][k];
        z2s[row][j] = tanh_fast(s);
    }
    __syncthreads();
    if (t < 256) {
        int row = t >> 4, o = t & 15;
        float s = mlp_b3[o];
        for (int k = 0; k < 100; k++) s += w3t[k * 16 + o] * z2s[row][k];
        emb_s[row][o] = s;
    }
    __syncthreads();

    // s4b (bias6, samp = emb @ WsampT): h3b -> h4b (buf0)
    gemm(2);
    #pragma unroll
    for (int h = 0; h < 2; h++) {
        const int unit = U + h * 16 + ln;
        float pre[4][4];
        #pragma unroll
        for (int g = 0; g < 4; g++) {
            uint2 pv = *(const uint2*)&ps_t[(g * 256 + unit) * 20 + q * 4];
            float bg = bias_all[6 * 1024 + g * 256 + unit];
            pre[g][0] = acc[g][h][0] + bf2f((ushort_t)(pv.x & 0xffffu)) + bg;
            pre[g][1] = acc[g][h][1] + bf2f((ushort_t)(pv.x >> 16)) + bg;
            pre[g][2] = acc[g][h][2] + bf2f((ushort_t)(pv.y & 0xffffu)) + bg;
            pre[g][3] = acc[g][h][3] + bf2f((ushort_t)(pv.y >> 16)) + bg;
        }
        #pragma unroll
        for (int k = 0; k < 16; k++) {
            float wv[4];
            #pragma unroll
            for (int g = 0; g < 4; g++) wv[g] = WsampT[(size_t)k * 1024 + g * 256 + unit];
            #pragma unroll
            for (int j = 0; j < 4; j++) {
                float e = emb_s[q * 4 + j][k];
                #pragma unroll
                for (int g = 0; g < 4; g++) pre[g][j] += e * wv[g];
            }
        }
        #pragma unroll
        for (int j = 0; j < 4; j++) {
            float ci = cB[j * 2 + h];
            float c2 = sigf(pre[1][j]) * ci + sigf(pre[0][j]) * tanh_fast(pre[2][j]);
            float hv = sigf(pre[3][j]) * tanh_fast(c2);
            hbuf[0][(q * 4 + j) * 272 + unit] = f2bf(hv);
        }
    }
    __syncthreads();

    // rp1 on h4b -> cols 13..14
    head_rp_f(hbuf[0], rp_ext_w, rp_ext_b, eps_rp1, 13, red, hdr, out, nullptr, b0, t);
}

// ---------------------------------------------------------------------------
extern "C" void kernel_launch(void* const* d_in, const int* in_sizes, int n_in,
                              void* d_out, int out_size, void* d_ws, size_t ws_size,
                              hipStream_t stream)
{
    const float* obs        = (const float*)d_in[0];
    const int*   program_id = (const int*)d_in[1];
    const int*   shape_id   = (const int*)d_in[2];
    const int*   shape_id_0 = (const int*)d_in[3];
    const int*   shape_id_1 = (const int*)d_in[4];
    const float* eps_rp     = (const float*)d_in[5];
    const float* eps_rp0    = (const float*)d_in[6];
    const float* eps_rp1    = (const float*)d_in[7];
    const float* conv1_w    = (const float*)d_in[8];
    const float* conv1_b    = (const float*)d_in[9];
    const float* conv2_w    = (const float*)d_in[10];
    const float* conv2_b    = (const float*)d_in[11];
    const float* mlp_w1     = (const float*)d_in[12];
    const float* mlp_b1     = (const float*)d_in[13];
    const float* mlp_w2     = (const float*)d_in[14];
    const float* mlp_b2     = (const float*)d_in[15];
    const float* mlp_w3     = (const float*)d_in[16];
    const float* mlp_b3     = (const float*)d_in[17];
    const float* W_ih       = (const float*)d_in[18];
    const float* b_ih       = (const float*)d_in[19];
    const float* W_hh       = (const float*)d_in[20];
    const float* b_hh       = (const float*)d_in[21];
    const float* addr_emb   = (const float*)d_in[22];
    const float* pid_emb    = (const float*)d_in[23];
    const float* sid_emb    = (const float*)d_in[24];
    const float* pid_ext_w  = (const float*)d_in[25];
    const float* pid_ext_b  = (const float*)d_in[26];
    const float* sid_ext_w  = (const float*)d_in[27];
    const float* sid_ext_b  = (const float*)d_in[28];
    const float* rp_ext_w   = (const float*)d_in[29];
    const float* rp_ext_b   = (const float*)d_in[30];
    float* out = (float*)d_out;

    // workspace layout
    float* ws = (float*)d_ws;
    size_t off = 0;
    float* W_ih_T   = ws + off; off += 432 * 1024;              // fp32 (WsampT source)
    ushort_t* Wb    = (ushort_t*)(ws + off); off += 131072;     // bf16 1024x256
    float* bias_all = ws + off; off += 7 * 1024;
    float* pid_rows = ws + off; off += 3 * 1024;
    float* sid_rows = ws + off; off += 2 * 1024;
    ushort_t* obs_emb_b = (ushort_t*)(ws + off); off += (size_t)BATCH * AK / 2;  // bf16 Bx448
    ushort_t* Wobs_b    = (ushort_t*)(ws + off); off += (size_t)1024 * AK / 2;   // bf16 1024x448
    ushort_t* obs_part = (ushort_t*)(ws + off); off += (size_t)BATCH * 512;      // bf16 Bx1024
    float* w2t = ws + off; off += 10000;
    float* w3t = ws + off; off += 1600;
    float* w1pp = ws + off; off += 384;
    ushort_t* Btg = (ushort_t*)(ws + off); off += 2304;
    float* WsampT = W_ih_T + (size_t)400 * 1024;  // rows 400..415 of W_ih_T

    prep_kernel<<<68, 256, 0, stream>>>(W_ih, W_hh, b_ih, b_hh, addr_emb,
                                        pid_emb, sid_emb, mlp_w2, mlp_w3,
                                        conv1_w, conv1_b, conv2_w,
                                        W_ih_T, Wb, bias_all, pid_rows,
                                        sid_rows, w2t, w3t, w1pp, Btg, Wobs_b);
    conv_kernel<<<BATCH, 512, 0, stream>>>(obs, w1pp, Btg, conv2_b, obs_emb_b);
    obs_gemm<<<512, 256, 0, stream>>>(obs_emb_b, Wobs_b, obs_part);
    lstm_chain<<<256, 512, 0, stream>>>(
        obs_part, bias_all, pid_rows, sid_rows,
        program_id, shape_id, shape_id_0, shape_id_1, Wb, WsampT,
        pid_ext_w, pid_ext_b, sid_ext_w, sid_ext_b, rp_ext_w, rp_ext_b,
        eps_rp, eps_rp0, eps_rp1,
        mlp_w1, mlp_b1, w2t, mlp_b2, w3t, mlp_b3, out);
}